// Round 8
// baseline (937.245 us; speedup 1.0000x reference)
//
#include <hip/hip_runtime.h>
#include <hip/hip_bf16.h>
#include <math.h>

#define B_ 8
#define T_ 1024
#define D_ 256
#define NH_ 4
#define N_ 256
#define EPS_ 1e-5f

typedef __attribute__((ext_vector_type(8))) short short8_t;
typedef __attribute__((ext_vector_type(4))) float floatx4;

__device__ inline unsigned short f2bf(float f) {
    unsigned u = __builtin_bit_cast(unsigned, f);
    u += 0x7FFFu + ((u >> 16) & 1u);          // round-to-nearest-even
    return (unsigned short)(u >> 16);
}
__device__ inline float bf2f(unsigned short h) {
    return __builtin_bit_cast(float, (unsigned)h << 16);
}

// async global->LDS, 16 B per lane; lds base wave-uniform, HW adds lane*16
__device__ inline void gload_lds16(const unsigned short* g, unsigned short* l) {
    __builtin_amdgcn_global_load_lds(
        (const __attribute__((address_space(1))) unsigned int*)g,
        (__attribute__((address_space(3))) unsigned int*)l, 16, 0, 0);
}

// ---------- helpers ----------
__device__ inline float2 block_stats_256(float v, float* red) {
    float s1 = v, s2 = v * v;
    #pragma unroll
    for (int o = 32; o > 0; o >>= 1) { s1 += __shfl_down(s1, o); s2 += __shfl_down(s2, o); }
    int wave = threadIdx.x >> 6, lane = threadIdx.x & 63;
    __syncthreads();
    if (lane == 0) { red[wave] = s1; red[4 + wave] = s2; }
    __syncthreads();
    float S1 = red[0] + red[1] + red[2] + red[3];
    float S2 = red[4] + red[5] + red[6] + red[7];
    float mean = S1 * (1.f / 256.f);
    float var  = S2 * (1.f / 256.f) - mean * mean;
    return make_float2(mean, var);
}

// ---------- weight transpose + split ----------
__global__ __launch_bounds__(256) void k_wT(
    const float* __restrict__ in, unsigned short* __restrict__ outh,
    unsigned short* __restrict__ outl, int R, int C)
{
    __shared__ float tile[64][65];
    int c0 = blockIdx.x * 64, r0 = blockIdx.y * 64, h = blockIdx.z;
    in += (size_t)h * R * C;
    for (int i = threadIdx.x; i < 4096; i += 256) {
        int r = i >> 6, c = i & 63;
        tile[r][c] = in[(size_t)(r0 + r) * C + c0 + c];
    }
    __syncthreads();
    for (int i = threadIdx.x; i < 4096; i += 256) {
        int c = i >> 6, r = i & 63;
        float v = tile[r][c];
        unsigned short hb = f2bf(v);
        size_t o = (size_t)(h * C + c0 + c) * R + r0 + r;
        outh[o] = hb;
        outl[o] = f2bf(v - bf2f(hb));
    }
}

// ---------- input projection + LN (+ bf16 hi/lo split of x) ----------
__global__ __launch_bounds__(256) void k_input_ln(
    const float* __restrict__ inputs, const float* __restrict__ in_w,
    const float* __restrict__ in_b, float* __restrict__ x,
    unsigned short* __restrict__ xh, unsigned short* __restrict__ xl)
{
    __shared__ float red[8];
    int row = blockIdx.x;
    int d = threadIdx.x;
    float v = inputs[row] * in_w[d] + in_b[d];
    float2 mv = block_stats_256(v, red);
    float o = (v - mv.x) * rsqrtf(mv.y + EPS_);
    size_t idx = (size_t)row * D_ + d;
    x[idx] = o;
    unsigned short hb = f2bf(o);
    xh[idx] = hb;
    xl[idx] = f2bf(o - bf2f(hb));
}

// ---------- split-bf16 MFMA GEMM (MODE 0: x @ encoder, fused relu+rope) ----------
template<int MODE>
__global__ __launch_bounds__(256, 2) void k_gemm_mfma(
    const unsigned short* __restrict__ Ah, const unsigned short* __restrict__ Al,
    const unsigned short* __restrict__ Wh, const unsigned short* __restrict__ Wl,
    unsigned short* __restrict__ outh, unsigned short* __restrict__ outl,
    unsigned short* __restrict__ qrh, unsigned short* __restrict__ qrl)
{
    constexpr int K = 256;
    __shared__ unsigned short As_h[8 * 512], As_l[8 * 512];
    __shared__ unsigned short Ws_h[8 * 512], Ws_l[8 * 512];
    int tid = threadIdx.x;
    int w = tid >> 6, lane = tid & 63, quad = lane >> 4, l16 = lane & 15;
    int wm = w >> 1, wn = w & 1;
    int m0 = blockIdx.y * 128, n0x = blockIdx.x * 128;
    size_t a_row0 = m0, w_row0 = n0x, out_row0 = m0;
    int col0 = n0x;
    floatx4 acc[4][4];
    #pragma unroll
    for (int mt = 0; mt < 4; mt++)
        #pragma unroll
        for (int nt = 0; nt < 4; nt++)
            acc[mt][nt] = (floatx4){0.f, 0.f, 0.f, 0.f};

    const unsigned short* ssrc = (w == 0) ? Ah : (w == 1) ? Al : (w == 2) ? Wh : Wl;
    unsigned short* sdst = (w == 0) ? As_h : (w == 1) ? As_l : (w == 2) ? Ws_h : Ws_l;
    size_t srow0 = (w < 2) ? a_row0 : w_row0;

    for (int k0 = 0; k0 < K; k0 += 32) {
        #pragma unroll
        for (int rt = 0; rt < 8; rt++) {
            size_t g = (srow0 + rt * 16 + l16) * (size_t)K + k0 + quad * 8;
            gload_lds16(ssrc + g, sdst + rt * 512);
        }
        __syncthreads();
        short8_t afh[4], afl[4], bfh[4], bfl[4];
        #pragma unroll
        for (int mt = 0; mt < 4; mt++) {
            afh[mt] = *(const short8_t*)&As_h[(wm * 4 + mt) * 512 + lane * 8];
            afl[mt] = *(const short8_t*)&As_l[(wm * 4 + mt) * 512 + lane * 8];
        }
        #pragma unroll
        for (int nt = 0; nt < 4; nt++) {
            bfh[nt] = *(const short8_t*)&Ws_h[(wn * 4 + nt) * 512 + lane * 8];
            bfl[nt] = *(const short8_t*)&Ws_l[(wn * 4 + nt) * 512 + lane * 8];
        }
        #pragma unroll
        for (int mt = 0; mt < 4; mt++)
            #pragma unroll
            for (int nt = 0; nt < 4; nt++) {
                acc[mt][nt] = __builtin_amdgcn_mfma_f32_16x16x32_bf16(afh[mt], bfh[nt], acc[mt][nt], 0, 0, 0);
                acc[mt][nt] = __builtin_amdgcn_mfma_f32_16x16x32_bf16(afh[mt], bfl[nt], acc[mt][nt], 0, 0, 0);
                acc[mt][nt] = __builtin_amdgcn_mfma_f32_16x16x32_bf16(afl[mt], bfh[nt], acc[mt][nt], 0, 0, 0);
            }
        __syncthreads();
    }

    #pragma unroll
    for (int mt = 0; mt < 4; mt++) {
        #pragma unroll
        for (int r = 0; r < 4; r++) {
            size_t grow = out_row0 + wm * 64 + mt * 16 + quad * 4 + r;
            #pragma unroll
            for (int nt = 0; nt < 4; nt++) {
                int gcol = col0 + wn * 64 + nt * 16 + l16;
                float v = acc[mt][nt][r];
                v = fmaxf(v, 0.f);
                size_t o = grow * 1024 + gcol;
                unsigned short hb = f2bf(v);
                outh[o] = hb;
                outl[o] = f2bf(v - bf2f(hb));
                // fused rope: partner col (n^1) lives in lane l16^1
                float vp = __shfl_xor(v, 1);
                int n = gcol & 255, h = gcol >> 8;
                int t = (int)(grow & 1023), b = (int)(grow >> 10);
                int p = n >> 1, j = p & 63;
                int pos = (p < 64) ? (t & 31) : (t >> 5);
                float f = __expf((float)j * -0.14391156f);
                float ang = (float)pos * f;
                float sn = __sinf(ang), cs = __cosf(ang);
                float ro = (n & 1) ? (vp * sn + v * cs) : (v * cs - vp * sn);
                size_t qo = (((size_t)b * NH_ + h) * T_ + t) * N_ + n;
                unsigned short qb = f2bf(ro);
                qrh[qo] = qb;
                qrl[qo] = f2bf(ro - bf2f(qb));
            }
        }
    }
}

// ---------- FUSED MODE1+MODE2: y_sparse -> xy (through LDS) -> ymlp partial ----------
// One block = 128 T-rows x one head (bh). Phase 1: acc = ykv @ evT^T (N=256,
// K=256), bit-identical fragments/K-order to the old MODE1. Phase 2: for each
// 32-col xy chunk, the 2 owning waves compute xy = relu(acc)*xs (hi/lo split,
// value-identical to the old global round-trip) and scatter into frag-order
// LDS; all waves stage the decT chunk; 48 MFMA into acc2. Chunk order, per-
// element K-order and 3-term order match old MODE2 with kz=h -> ymlp partial
// h is BIT-IDENTICAL; k_resid_ln unchanged. Eliminates xy global write+read
// and one launch per layer. LDS 96 KB (two double-buffered phases share one
// 2x24576-short arena; slot layout: [0,4K)=A/xyA_h, [4K,8K)=A/xyA_l,
// [8K,16K)=W/W2_h, [16K,24K)=W/W2_l).
__global__ __launch_bounds__(512, 1) void k_gemm_fused(
    const unsigned short* __restrict__ Ah, const unsigned short* __restrict__ Al,
    const unsigned short* __restrict__ Wh, const unsigned short* __restrict__ Wl,
    const unsigned short* __restrict__ D2h, const unsigned short* __restrict__ D2l,
    const unsigned short* __restrict__ xsh, const unsigned short* __restrict__ xsl,
    float* __restrict__ outf)
{
    __shared__ unsigned short SM[2][24576];   // 96 KB
    int tid = threadIdx.x;
    int w = tid >> 6, lane = tid & 63, quad = lane >> 4, l16 = lane & 15;
    int wm = w >> 2, wn = w & 3;
    int m0 = blockIdx.x * 128;
    int bh = blockIdx.y, b = bh >> 2, h = bh & 3;
    size_t a_row0 = (size_t)bh * 1024 + m0;
    size_t w_row0 = (size_t)h * 256;
    size_t xrow0  = (size_t)b * 1024 + m0;

    floatx4 acc[4][4];
    #pragma unroll
    for (int mt = 0; mt < 4; mt++)
        #pragma unroll
        for (int nt = 0; nt < 4; nt++)
            acc[mt][nt] = (floatx4){0.f, 0.f, 0.f, 0.f};

    // staging helper (phase 1): 48 slots/step (A_h8, A_l8, W_h16, W_l16), 6/wave
    auto stage_main = [&](int k0, int bw) {
        #pragma unroll
        for (int t = 0; t < 6; t++) {
            int idx = w * 6 + t;
            const unsigned short* src; unsigned short* dst; size_t rowb; int rt;
            if (idx < 8)       { rt = idx;      src = Ah; dst = &SM[bw][0];     rowb = a_row0; }
            else if (idx < 16) { rt = idx - 8;  src = Al; dst = &SM[bw][4096];  rowb = a_row0; }
            else if (idx < 32) { rt = idx - 16; src = Wh; dst = &SM[bw][8192];  rowb = w_row0; }
            else               { rt = idx - 32; src = Wl; dst = &SM[bw][16384]; rowb = w_row0; }
            gload_lds16(src + (rowb + rt * 16 + l16) * 256 + k0 + quad * 8, dst + rt * 512);
        }
    };

    // ---- phase 1: acc = ykv(128) x evT(256)^T over K=256 ----
    stage_main(0, 0);
    for (int s = 0; s < 8; s++) {
        int buf = s & 1;
        __syncthreads();                       // tile s ready
        if (s < 7) stage_main((s + 1) * 32, buf ^ 1);
        short8_t afh[4], afl[4], bfh[4], bfl[4];
        #pragma unroll
        for (int mt = 0; mt < 4; mt++) {
            afh[mt] = *(const short8_t*)&SM[buf][(wm * 4 + mt) * 512 + lane * 8];
            afl[mt] = *(const short8_t*)&SM[buf][4096 + (wm * 4 + mt) * 512 + lane * 8];
        }
        #pragma unroll
        for (int nt = 0; nt < 4; nt++) {
            bfh[nt] = *(const short8_t*)&SM[buf][8192  + (wn * 4 + nt) * 512 + lane * 8];
            bfl[nt] = *(const short8_t*)&SM[buf][16384 + (wn * 4 + nt) * 512 + lane * 8];
        }
        #pragma unroll
        for (int mt = 0; mt < 4; mt++)
            #pragma unroll
            for (int nt = 0; nt < 4; nt++) {
                acc[mt][nt] = __builtin_amdgcn_mfma_f32_16x16x32_bf16(afh[mt], bfh[nt], acc[mt][nt], 0, 0, 0);
                acc[mt][nt] = __builtin_amdgcn_mfma_f32_16x16x32_bf16(afh[mt], bfl[nt], acc[mt][nt], 0, 0, 0);
                acc[mt][nt] = __builtin_amdgcn_mfma_f32_16x16x32_bf16(afl[mt], bfh[nt], acc[mt][nt], 0, 0, 0);
            }
    }
    // after loop: all buf0 reads retired (s=7's top barrier); s=7 reads buf1 only.

    // ---- phase 2 helpers ----
    // owning waves (wn == c>>1) compute xy for chunk c's 32 cols -> frag-order LDS
    auto write_xy = [&](int c, int bw) {
        if (wn != (c >> 1)) return;
        int cb = c & 1;
        #pragma unroll
        for (int mt = 0; mt < 4; mt++)
            #pragma unroll
            for (int nt = 0; nt < 4; nt++) {
                if ((nt >> 1) != cb) continue;       // static acc index (rule #20)
                #pragma unroll
                for (int r = 0; r < 4; r++) {
                    float v = fmaxf(acc[mt][nt][r], 0.f);
                    size_t grow = xrow0 + wm * 64 + mt * 16 + quad * 4 + r;
                    int gcol = h * 256 + wn * 64 + nt * 16 + l16;
                    size_t o = grow * 1024 + gcol;
                    float xv = bf2f(xsh[o]) + bf2f(xsl[o]);
                    float p = xv * v;
                    unsigned short ph = f2bf(p);
                    int kin = (nt & 1) * 16 + l16;   // col within chunk
                    int ad = (wm * 4 + mt) * 512 + (kin >> 3) * 128 + (quad * 4 + r) * 8 + (kin & 7);
                    SM[bw][ad] = ph;
                    SM[bw][4096 + ad] = f2bf(p - bf2f(ph));
                }
            }
    };
    // all waves stage decT chunk c: 32 slots (W2_h16, W2_l16), 4/wave
    auto stage_w2 = [&](int c, int bw) {
        #pragma unroll
        for (int t = 0; t < 4; t++) {
            int idx = w * 4 + t;
            const unsigned short* src = (idx < 16) ? D2h : D2l;
            unsigned short* dst = (idx < 16) ? &SM[bw][8192] : &SM[bw][16384];
            int rt = idx & 15;
            gload_lds16(src + (size_t)(rt * 16 + l16) * 1024 + h * 256 + c * 32 + quad * 8,
                        dst + rt * 512);
        }
    };

    // ---- phase 2: acc2 = xy(128 x K256, from LDS) x decT_h(256)^T ----
    floatx4 acc2[4][4];
    #pragma unroll
    for (int mt = 0; mt < 4; mt++)
        #pragma unroll
        for (int nt = 0; nt < 4; nt++)
            acc2[mt][nt] = (floatx4){0.f, 0.f, 0.f, 0.f};

    write_xy(0, 0);
    stage_w2(0, 0);
    #pragma unroll
    for (int c = 0; c < 8; c++) {
        int buf = c & 1;
        __syncthreads();                       // xy(c) + W2(c) ready
        if (c < 7) { write_xy(c + 1, buf ^ 1); stage_w2(c + 1, buf ^ 1); }
        short8_t b2h[4], b2l[4];
        #pragma unroll
        for (int nt = 0; nt < 4; nt++) {
            b2h[nt] = *(const short8_t*)&SM[buf][8192  + (wn * 4 + nt) * 512 + lane * 8];
            b2l[nt] = *(const short8_t*)&SM[buf][16384 + (wn * 4 + nt) * 512 + lane * 8];
        }
        #pragma unroll
        for (int mt = 0; mt < 4; mt++) {
            short8_t a2h = *(const short8_t*)&SM[buf][(wm * 4 + mt) * 512 + lane * 8];
            short8_t a2l = *(const short8_t*)&SM[buf][4096 + (wm * 4 + mt) * 512 + lane * 8];
            #pragma unroll
            for (int nt = 0; nt < 4; nt++) {
                acc2[mt][nt] = __builtin_amdgcn_mfma_f32_16x16x32_bf16(a2h, b2h[nt], acc2[mt][nt], 0, 0, 0);
                acc2[mt][nt] = __builtin_amdgcn_mfma_f32_16x16x32_bf16(a2h, b2l[nt], acc2[mt][nt], 0, 0, 0);
                acc2[mt][nt] = __builtin_amdgcn_mfma_f32_16x16x32_bf16(a2l, b2h[nt], acc2[mt][nt], 0, 0, 0);
            }
        }
    }

    // ---- epilogue: ymlp partial for head h (same slot old kz=h used) ----
    #pragma unroll
    for (int mt = 0; mt < 4; mt++)
        #pragma unroll
        for (int r = 0; r < 4; r++) {
            size_t grow = xrow0 + wm * 64 + mt * 16 + quad * 4 + r;
            #pragma unroll
            for (int nt = 0; nt < 4; nt++)
                outf[(size_t)h * 2097152 + grow * 256 + wn * 64 + nt * 16 + l16] = acc2[mt][nt][r];
        }
}

// ---------- x (B,T,D) fp32 -> Vf hi/lo fragment-order bf16 ----------
__global__ __launch_bounds__(256) void k_xT(const float* __restrict__ x,
                                            unsigned short* __restrict__ Vfh,
                                            unsigned short* __restrict__ Vfl)
{
    __shared__ float tile[64][65];   // [t_local][d_local]
    int t0 = blockIdx.x * 64, d0 = blockIdx.y * 64, b = blockIdx.z;
    const float* src = x + ((size_t)b * T_ + t0) * D_ + d0;
    for (int i = threadIdx.x; i < 1024; i += 256) {
        int r = i >> 4, c = i & 15;
        float4 v = *(const float4*)(src + (size_t)r * D_ + c * 4);
        tile[r][c * 4 + 0] = v.x;
        tile[r][c * 4 + 1] = v.y;
        tile[r][c * 4 + 2] = v.z;
        tile[r][c * 4 + 3] = v.w;
    }
    __syncthreads();
    for (int i = threadIdx.x; i < 1024; i += 256) {
        int d = i >> 4, c = i & 15;          // d_local, t-group (4 consecutive t)
        int tg = t0 + c * 4;
        int jj = tg >> 5, qd = (tg >> 3) & 3, i8 = tg & 7;   // i8 in {0,4}
        int dg = d0 + d;
        int tn = dg >> 4, s16 = dg & 15;
        size_t o = (((size_t)b * 32 + jj) * 16 + tn) * 512 + (qd * 16 + s16) * 8 + i8;
        float v0 = tile[c * 4 + 0][d], v1 = tile[c * 4 + 1][d];
        float v2 = tile[c * 4 + 2][d], v3 = tile[c * 4 + 3][d];
        ushort4 oh, ol;
        oh.x = f2bf(v0); ol.x = f2bf(v0 - bf2f(oh.x));
        oh.y = f2bf(v1); ol.y = f2bf(v1 - bf2f(oh.y));
        oh.z = f2bf(v2); ol.z = f2bf(v2 - bf2f(oh.z));
        oh.w = f2bf(v3); ol.w = f2bf(v3 - bf2f(oh.w));
        *(ushort4*)(Vfh + o) = oh;
        *(ushort4*)(Vfl + o) = ol;
    }
}

// ---------- fused split-bf16 MFMA flash attention + /l + LayerNorm ----------
// Exact R5 kernel (best measured: 125.0 us). Pair-split geometry.
#define PPW2 36   // P row pitch (32 cols + 4 pad)

__global__ __launch_bounds__(512, 1) void k_attn_mfma(
    const unsigned short* __restrict__ qr_h, const unsigned short* __restrict__ qr_l,
    const unsigned short* __restrict__ Vf_h, const unsigned short* __restrict__ Vf_l,
    unsigned short* __restrict__ ykvh, unsigned short* __restrict__ ykvl)
{
    __shared__ unsigned short K_h[2][16 * 512];   // 32 KB (2 buf, frag order)
    __shared__ unsigned short K_l[2][16 * 512];   // 32 KB
    __shared__ unsigned short V_h[2][16 * 512];   // 32 KB
    __shared__ unsigned short V_l[2][16 * 512];   // 32 KB
    __shared__ unsigned short P_h[4][32 * PPW2];  // 9216 B (per row-group)
    __shared__ unsigned short P_l[4][32 * PPW2];  // 9216 B
    __shared__ float l_scr[8][32];                // per-wave partial row sums
    __shared__ float s1_scr[8][32];               // per-wave partial LN stats
    __shared__ float s2_scr[8][32];

    int tid = threadIdx.x;
    int w = tid >> 6, lane = tid & 63, quad = lane >> 4, l16 = lane & 15;
    int rg = w >> 1, half = w & 1;
    int gid = blockIdx.x;
    int bh = gid & 31, tile = gid >> 5, b = bh >> 2;   // XCD swizzle: same-bh
    int t0q = tile * 128;                              // blocks share an XCD
    const unsigned short* qhb = qr_h + (size_t)bh * T_ * N_;
    const unsigned short* qlb = qr_l + (size_t)bh * T_ * N_;
    const unsigned short* vhb = Vf_h + (size_t)b * 32 * 16 * 512;
    const unsigned short* vlb = Vf_l + (size_t)b * 32 * 16 * 512;

    // Q A-frags: row-group's 32 rows (2 tiles of 16), full feature dim, hi+lo
    short8_t qfh[2][8], qfl[2][8];
    #pragma unroll
    for (int mt = 0; mt < 2; mt++)
        #pragma unroll
        for (int kc = 0; kc < 8; kc++) {
            size_t o = (size_t)(t0q + rg * 32 + mt * 16 + l16) * N_ + kc * 32 + quad * 8;
            qfh[mt][kc] = *(const short8_t*)(qhb + o);
            qfl[mt][kc] = *(const short8_t*)(qlb + o);
        }

    floatx4 O[2][8];                 // 32 rows x 128 cols (this wave's D-half)
    #pragma unroll
    for (int mt = 0; mt < 2; mt++)
        #pragma unroll
        for (int t = 0; t < 8; t++) O[mt][t] = (floatx4){0.f, 0.f, 0.f, 0.f};
    float lst[2][4] = {{0.f, 0.f, 0.f, 0.f}, {0.f, 0.f, 0.f, 0.f}};
    const float scale = 0.0625f;   // 1/sqrt(256)

    // preamble: stage K and V tile 0 into buffer 0 (wave w: slots 2w, 2w+1)
    #pragma unroll
    for (int s = 0; s < 2; s++) {
        int slot = w * 2 + s;
        int ct = slot >> 3, kc = slot & 7;
        size_t go = (size_t)(ct * 16 + l16) * N_ + kc * 32 + quad * 8;
        gload_lds16(qhb + go, &K_h[0][slot * 512]);
        gload_lds16(qlb + go, &K_l[0][slot * 512]);
        size_t vo = ((size_t)slot << 9) + lane * 8;
        gload_lds16(vhb + vo, &V_h[0][slot * 512]);
        gload_lds16(vlb + vo, &V_l[0][slot * 512]);
    }

    for (int j = 0; j < 32; j++) {
        int buf = j & 1;
        __syncthreads();            // [top] K(j),V(j) ready; drains K(j) loads
        if (j < 31) {               // stage V(j+1): lands during QK
            #pragma unroll
            for (int s = 0; s < 2; s++) {
                int slot = w * 2 + s;
                size_t vo = ((size_t)((j + 1) * 16 + slot) << 9) + lane * 8;
                gload_lds16(vhb + vo, &V_h[buf ^ 1][slot * 512]);
                gload_lds16(vlb + vo, &V_l[buf ^ 1][slot * 512]);
            }
        }

        // QK^T: this wave's 16 cols (ct = half) for 32 rows; 6 indep chains
        floatx4 a_hh0 = (floatx4){0.f, 0.f, 0.f, 0.f};
        floatx4 a_hl0 = (floatx4){0.f, 0.f, 0.f, 0.f};
        floatx4 a_lh0 = (floatx4){0.f, 0.f, 0.f, 0.f};
        floatx4 a_hh1 = (floatx4){0.f, 0.f, 0.f, 0.f};
        floatx4 a_hl1 = (floatx4){0.f, 0.f, 0.f, 0.f};
        floatx4 a_lh1 = (floatx4){0.f, 0.f, 0.f, 0.f};
        __builtin_amdgcn_s_setprio(1);
        #pragma unroll
        for (int kc = 0; kc < 8; kc++) {
            short8_t bkh = *(const short8_t*)&K_h[buf][(half * 8 + kc) * 512 + lane * 8];
            short8_t bkl = *(const short8_t*)&K_l[buf][(half * 8 + kc) * 512 + lane * 8];
            a_hh0 = __builtin_amdgcn_mfma_f32_16x16x32_bf16(qfh[0][kc], bkh, a_hh0, 0, 0, 0);
            a_hh1 = __builtin_amdgcn_mfma_f32_16x16x32_bf16(qfh[1][kc], bkh, a_hh1, 0, 0, 0);
            a_hl0 = __builtin_amdgcn_mfma_f32_16x16x32_bf16(qfh[0][kc], bkl, a_hl0, 0, 0, 0);
            a_hl1 = __builtin_amdgcn_mfma_f32_16x16x32_bf16(qfh[1][kc], bkl, a_hl1, 0, 0, 0);
            a_lh0 = __builtin_amdgcn_mfma_f32_16x16x32_bf16(qfl[0][kc], bkh, a_lh0, 0, 0, 0);
            a_lh1 = __builtin_amdgcn_mfma_f32_16x16x32_bf16(qfl[1][kc], bkh, a_lh1, 0, 0, 0);
        }
        __builtin_amdgcn_s_setprio(0);
        floatx4 sc0 = (a_hh0 + a_hl0) + a_lh0;
        floatx4 sc1 = (a_hh1 + a_hl1) + a_lh1;

        // fixed-shift softmax; write this wave's 16 cols into the rg P tile
        #pragma unroll
        for (int r = 0; r < 4; r++) {
            float p0 = __expf(sc0[r] * scale - 8.f);
            float p1 = __expf(sc1[r] * scale - 8.f);
            lst[0][r] += p0;
            lst[1][r] += p1;
            int row0 = quad * 4 + r, row1 = 16 + quad * 4 + r;
            unsigned short p0h = f2bf(p0), p1h = f2bf(p1);
            P_h[rg][row0 * PPW2 + half * 16 + l16] = p0h;
            P_h[rg][row1 * PPW2 + half * 16 + l16] = p1h;
            P_l[rg][row0 * PPW2 + half * 16 + l16] = f2bf(p0 - bf2f(p0h));
            P_l[rg][row1 * PPW2 + half * 16 + l16] = f2bf(p1 - bf2f(p1h));
        }

        __syncthreads();            // [mid] P complete (both halves); drains V(j+1)
        if (j < 31) {               // stage K(j+1): lands during PV
            #pragma unroll
            for (int s = 0; s < 2; s++) {
                int slot = w * 2 + s;
                int ct = slot >> 3, kc = slot & 7;
                size_t go = (size_t)((j + 1) * 32 + ct * 16 + l16) * N_ + kc * 32 + quad * 8;
                gload_lds16(qhb + go, &K_h[buf ^ 1][slot * 512]);
                gload_lds16(qlb + go, &K_l[buf ^ 1][slot * 512]);
            }
        }

        // P A-frags: full 32 cols (both halves) for both row tiles
        short8_t pah0 = *(const short8_t*)&P_h[rg][(l16) * PPW2 + quad * 8];
        short8_t pal0 = *(const short8_t*)&P_l[rg][(l16) * PPW2 + quad * 8];
        short8_t pah1 = *(const short8_t*)&P_h[rg][(16 + l16) * PPW2 + quad * 8];
        short8_t pal1 = *(const short8_t*)&P_l[rg][(16 + l16) * PPW2 + quad * 8];

        // PV: this wave's D-half (tn = half*8 + t); 3-term split, bit-identical
        __builtin_amdgcn_s_setprio(1);
        #pragma unroll
        for (int t = 0; t < 8; t++) {
            int tn = half * 8 + t;
            short8_t vbh = *(const short8_t*)&V_h[buf][tn * 512 + lane * 8];
            short8_t vbl = *(const short8_t*)&V_l[buf][tn * 512 + lane * 8];
            O[0][t] = __builtin_amdgcn_mfma_f32_16x16x32_bf16(pah0, vbh, O[0][t], 0, 0, 0);
            O[1][t] = __builtin_amdgcn_mfma_f32_16x16x32_bf16(pah1, vbh, O[1][t], 0, 0, 0);
            O[0][t] = __builtin_amdgcn_mfma_f32_16x16x32_bf16(pah0, vbl, O[0][t], 0, 0, 0);
            O[1][t] = __builtin_amdgcn_mfma_f32_16x16x32_bf16(pah1, vbl, O[1][t], 0, 0, 0);
            O[0][t] = __builtin_amdgcn_mfma_f32_16x16x32_bf16(pal0, vbh, O[0][t], 0, 0, 0);
            O[1][t] = __builtin_amdgcn_mfma_f32_16x16x32_bf16(pal1, vbh, O[1][t], 0, 0, 0);
        }
        __builtin_amdgcn_s_setprio(0);
    }

    // ---- epilogue: pair-merge l and LN stats through LDS, then write ----
    #pragma unroll
    for (int mt = 0; mt < 2; mt++)
        #pragma unroll
        for (int r = 0; r < 4; r++) {
            float ls = lst[mt][r];
            #pragma unroll
            for (int o = 1; o < 16; o <<= 1) ls += __shfl_xor(ls, o);
            float s1 = 0.f, s2 = 0.f;
            #pragma unroll
            for (int t = 0; t < 8; t++) { float v = O[mt][t][r]; s1 += v; s2 += v * v; }
            #pragma unroll
            for (int o = 1; o < 16; o <<= 1) { s1 += __shfl_xor(s1, o); s2 += __shfl_xor(s2, o); }
            int row = mt * 16 + quad * 4 + r;
            if (l16 == 0) { l_scr[w][row] = ls; s1_scr[w][row] = s1; s2_scr[w][row] = s2; }
        }
    __syncthreads();
    #pragma unroll
    for (int mt = 0; mt < 2; mt++)
        #pragma unroll
        for (int r = 0; r < 4; r++) {
            int row = mt * 16 + quad * 4 + r;
            float ls = l_scr[w][row] + l_scr[w ^ 1][row];
            float s1 = s1_scr[w][row] + s1_scr[w ^ 1][row];
            float s2 = s2_scr[w][row] + s2_scr[w ^ 1][row];
            float li = 1.f / ls;
            float mean = s1 * li * (1.f / 256.f);
            float e2   = s2 * li * li * (1.f / 256.f);
            float var  = e2 - mean * mean;
            float rs = rsqrtf(var + EPS_);
            float a = li * rs, bb = mean * rs;
            size_t obase = ((size_t)bh * T_ + t0q + rg * 32 + row) * D_;
            #pragma unroll
            for (int t = 0; t < 8; t++) {
                float v = O[mt][t][r] * a - bb;
                size_t o = obase + half * 128 + t * 16 + l16;
                unsigned short hb = f2bf(v);
                ykvh[o] = hb;
                ykvl[o] = f2bf(v - bf2f(hb));
            }
        }
}

// ---------- residual + double LN: sums 4 per-head partials of ymlp ----------
__global__ __launch_bounds__(256) void k_resid_ln(float* __restrict__ x,
                                                  const float* __restrict__ ymlp,
                                                  unsigned short* __restrict__ xh,
                                                  unsigned short* __restrict__ xl)
{
    __shared__ float red[8];
    int row = blockIdx.x, d = threadIdx.x;
    size_t o = (size_t)row * D_ + d;
    float y = ymlp[o] + ymlp[o + 2097152] + ymlp[o + 2 * 2097152] + ymlp[o + 3 * 2097152];
    float2 mv1 = block_stats_256(y, red);
    float v = x[o] + (y - mv1.x) * rsqrtf(mv1.y + EPS_);
    float2 mv2 = block_stats_256(v, red);
    float out = (v - mv2.x) * rsqrtf(mv2.y + EPS_);
    x[o] = out;
    unsigned short hb = f2bf(out);
    xh[o] = hb;
    xl[o] = f2bf(out - bf2f(hb));
}

// ---------- logits ----------
__global__ __launch_bounds__(256) void k_logits(
    const float* __restrict__ x, const float* __restrict__ out_w,
    const float* __restrict__ out_b, float* __restrict__ out)
{
    __shared__ float red[4];
    int row = blockIdx.x, d = threadIdx.x;
    float v = x[(size_t)row * D_ + d] * out_w[d];
    #pragma unroll
    for (int o = 32; o > 0; o >>= 1) v += __shfl_down(v, o);
    int wave = d >> 6, lane = d & 63;
    if (lane == 0) red[wave] = v;
    __syncthreads();
    if (d == 0) out[row] = red[0] + red[1] + red[2] + red[3] + out_b[0];
}

extern "C" void kernel_launch(void* const* d_in, const int* in_sizes, int n_in,
                              void* d_out, int out_size, void* d_ws, size_t ws_size,
                              hipStream_t stream)
{
    (void)in_sizes; (void)n_in; (void)out_size;
    if (ws_size < ((size_t)115 << 20)) return;

    const float* inputs    = (const float*)d_in[0];
    const float* in_w      = (const float*)d_in[1];
    const float* in_b      = (const float*)d_in[2];
    const float* encoder   = (const float*)d_in[3];
    const float* encoder_v = (const float*)d_in[4];
    const float* decoder   = (const float*)d_in[5];
    const float* out_w     = (const float*)d_in[6];
    const float* out_b     = (const float*)d_in[7];

    char* wsb = (char*)d_ws;
    float* x             = (float*)(wsb);                                 //  8 MB fp32 (B,T,D)
    unsigned short* x_h  = (unsigned short*)(wsb + ((size_t)8  << 20));   //  4 MB bf16 hi
    unsigned short* x_l  = (unsigned short*)(wsb + ((size_t)12 << 20));   //  4 MB lo
    unsigned short* Vf_h = x_h;                                           //  ALIAS (disjoint phases)
    unsigned short* Vf_l = x_l;
    unsigned short* xs_h = (unsigned short*)(wsb + ((size_t)16 << 20));   // 16 MB (B,T,NH*N) hi
    unsigned short* xs_l = (unsigned short*)(wsb + ((size_t)32 << 20));   // 16 MB lo
    unsigned short* qr_h = (unsigned short*)(wsb + ((size_t)48 << 20));   // 16 MB (B,NH,T,N) hi
    unsigned short* qr_l = (unsigned short*)(wsb + ((size_t)64 << 20));   // 16 MB lo
    float* ymlp          = (float*)(wsb + ((size_t)48 << 20));            // 32 MB fp32 x4 partials,
                                                                          //  ALIASES qr (dead after attn;
                                                                          //  rewritten next layer by gemm0)
    unsigned short* ykv_h = (unsigned short*)(wsb + ((size_t)80 << 20));  // 16 MB (B,NH,T,D) hi
    unsigned short* ykv_l = (unsigned short*)(wsb + ((size_t)96 << 20));  // 16 MB lo
    char* wbase = wsb + ((size_t)112 << 20);                              //  3 MB weights
    unsigned short* encT_h = (unsigned short*)(wbase);
    unsigned short* encT_l = (unsigned short*)(wbase + 0x80000);
    unsigned short* evT_h  = (unsigned short*)(wbase + 2 * 0x80000);
    unsigned short* evT_l  = (unsigned short*)(wbase + 3 * 0x80000);
    unsigned short* decT_h = (unsigned short*)(wbase + 4 * 0x80000);
    unsigned short* decT_l = (unsigned short*)(wbase + 5 * 0x80000);

    k_wT<<<dim3(4, 4, 4), 256, 0, stream>>>(encoder,   encT_h, encT_l, 256, 256);
    k_wT<<<dim3(4, 4, 4), 256, 0, stream>>>(encoder_v, evT_h,  evT_l,  256, 256);
    k_wT<<<dim3(4, 16, 1), 256, 0, stream>>>(decoder,  decT_h, decT_l, 1024, 256);

    k_input_ln<<<B_ * T_, 256, 0, stream>>>(inputs, in_w, in_b, x, x_h, x_l);
    for (int l = 0; l < 3; l++) {
        k_gemm_mfma<0><<<dim3(8, 64, 1), 256, 0, stream>>>(
            x_h, x_l, encT_h, encT_l, xs_h, xs_l, qr_h, qr_l);
        k_xT<<<dim3(16, 4, 8), 256, 0, stream>>>(x, Vf_h, Vf_l);
        k_attn_mfma<<<256, 512, 0, stream>>>(qr_h, qr_l, Vf_h, Vf_l, ykv_h, ykv_l);
        k_gemm_fused<<<dim3(8, 32), 512, 0, stream>>>(
            ykv_h, ykv_l, evT_h, evT_l, decT_h, decT_l, xs_h, xs_l, ymlp);
        k_resid_ln<<<B_ * T_, 256, 0, stream>>>(x, ymlp, x_h, x_l);
    }
    k_logits<<<B_ * T_, 256, 0, stream>>>(x, out_w, out_b, (float*)d_out);
}

// Round 10
// 715.101 us; speedup vs baseline: 1.3106x; 1.3106x over previous
//
#include <hip/hip_runtime.h>
#include <hip/hip_bf16.h>
#include <math.h>

#define B_ 8
#define T_ 1024
#define D_ 256
#define NH_ 4
#define N_ 256
#define EPS_ 1e-5f

typedef __attribute__((ext_vector_type(8))) short short8_t;
typedef __attribute__((ext_vector_type(4))) float floatx4;

__device__ inline unsigned short f2bf(float f) {
    unsigned u = __builtin_bit_cast(unsigned, f);
    u += 0x7FFFu + ((u >> 16) & 1u);          // round-to-nearest-even
    return (unsigned short)(u >> 16);
}
__device__ inline float bf2f(unsigned short h) {
    return __builtin_bit_cast(float, (unsigned)h << 16);
}

// async global->LDS, 16 B per lane; lds base wave-uniform, HW adds lane*16
__device__ inline void gload_lds16(const unsigned short* g, unsigned short* l) {
    __builtin_amdgcn_global_load_lds(
        (const __attribute__((address_space(1))) unsigned int*)g,
        (__attribute__((address_space(3))) unsigned int*)l, 16, 0, 0);
}

// ---------- helpers ----------
__device__ inline float2 block_stats_256(float v, float* red) {
    float s1 = v, s2 = v * v;
    #pragma unroll
    for (int o = 32; o > 0; o >>= 1) { s1 += __shfl_down(s1, o); s2 += __shfl_down(s2, o); }
    int wave = threadIdx.x >> 6, lane = threadIdx.x & 63;
    __syncthreads();
    if (lane == 0) { red[wave] = s1; red[4 + wave] = s2; }
    __syncthreads();
    float S1 = red[0] + red[1] + red[2] + red[3];
    float S2 = red[4] + red[5] + red[6] + red[7];
    float mean = S1 * (1.f / 256.f);
    float var  = S2 * (1.f / 256.f) - mean * mean;
    return make_float2(mean, var);
}

// ---------- weight transpose + split ----------
__global__ __launch_bounds__(256) void k_wT(
    const float* __restrict__ in, unsigned short* __restrict__ outh,
    unsigned short* __restrict__ outl, int R, int C)
{
    __shared__ float tile[64][65];
    int c0 = blockIdx.x * 64, r0 = blockIdx.y * 64, h = blockIdx.z;
    in += (size_t)h * R * C;
    for (int i = threadIdx.x; i < 4096; i += 256) {
        int r = i >> 6, c = i & 63;
        tile[r][c] = in[(size_t)(r0 + r) * C + c0 + c];
    }
    __syncthreads();
    for (int i = threadIdx.x; i < 4096; i += 256) {
        int c = i >> 6, r = i & 63;
        float v = tile[r][c];
        unsigned short hb = f2bf(v);
        size_t o = (size_t)(h * C + c0 + c) * R + r0 + r;
        outh[o] = hb;
        outl[o] = f2bf(v - bf2f(hb));
    }
}

// ---------- input projection + LN (+ bf16 hi/lo split of x) ----------
__global__ __launch_bounds__(256) void k_input_ln(
    const float* __restrict__ inputs, const float* __restrict__ in_w,
    const float* __restrict__ in_b, float* __restrict__ x,
    unsigned short* __restrict__ xh, unsigned short* __restrict__ xl)
{
    __shared__ float red[8];
    int row = blockIdx.x;
    int d = threadIdx.x;
    float v = inputs[row] * in_w[d] + in_b[d];
    float2 mv = block_stats_256(v, red);
    float o = (v - mv.x) * rsqrtf(mv.y + EPS_);
    size_t idx = (size_t)row * D_ + d;
    x[idx] = o;
    unsigned short hb = f2bf(o);
    xh[idx] = hb;
    xl[idx] = f2bf(o - bf2f(hb));
}

// ---------- split-bf16 MFMA GEMM (BK=32, PG-padded reg staging: best measured) ----------
// (256,2): 2 blocks/CU — co-resident block covers staging latency.
// MODE 0: epilogue FUSES rope -> writes qr hi/lo directly. sin/cos come from
//   a 16 KB LDS table built once per block with the SAME __expf/__sinf/__cosf
//   intrinsics (bit-identical values; replaces 48 transcendentals/thread in
//   the epilogue with 16 LDS reads). Visibility: 16 __syncthreads of the
//   K-loop sit between build and use. LDS 40+16=56 KB -> still 2 blocks/CU.
// MODE 2 split-K-4: blockIdx.z = kz, partials summed in k_resid_ln.
#define PG 40   // LDS pitch (32 + 8)
template<int MODE>
__global__ __launch_bounds__(256, 2) void k_gemm_mfma(
    const unsigned short* __restrict__ Ah, const unsigned short* __restrict__ Al,
    const unsigned short* __restrict__ Wh, const unsigned short* __restrict__ Wl,
    const unsigned short* __restrict__ xsh, const unsigned short* __restrict__ xsl,
    unsigned short* __restrict__ outh, unsigned short* __restrict__ outl,
    float* __restrict__ outf,
    unsigned short* __restrict__ qrh, unsigned short* __restrict__ qrl)
{
    constexpr int K = (MODE == 2) ? 1024 : 256;
    __shared__ unsigned short As_h[128 * PG], As_l[128 * PG];
    __shared__ unsigned short Ws_h[128 * PG], Ws_l[128 * PG];
    __shared__ float2 rtab_s[(MODE == 0) ? 2048 : 1];   // 16 KB (MODE0 only)
    int tid = threadIdx.x;
    int w = tid >> 6, lane = tid & 63, quad = lane >> 4, l16 = lane & 15;
    int wm = w >> 1, wn = w & 1;
    int m0 = blockIdx.y * 128, n0x = blockIdx.x * 128;
    size_t a_row0, w_row0, out_row0;
    int col0;
    int koff = 0, kend = K;
    if (MODE == 1) {
        int bh = blockIdx.z;
        a_row0 = (size_t)bh * 1024 + m0;
        w_row0 = (size_t)((bh & 3) * 256 + n0x);
        out_row0 = (size_t)(bh >> 2) * 1024 + m0;
        col0 = (bh & 3) * 256 + n0x;
    } else {
        a_row0 = m0; w_row0 = n0x; out_row0 = m0; col0 = n0x;
        if (MODE == 2) { koff = blockIdx.z * 256; kend = koff + 256; }
    }

    if (MODE == 0) {
        // build rope table: entry i=(j*32+pos); 8 entries/thread, same-j run
        #pragma unroll
        for (int it = 0; it < 8; it++) {
            int i = tid * 8 + it;
            int j = i >> 5, pos = i & 31;
            float f = __expf((float)j * -0.14391156f);
            float ang = (float)pos * f;
            rtab_s[i] = make_float2(__sinf(ang), __cosf(ang));
        }
    }

    floatx4 acc[4][4];
    #pragma unroll
    for (int mt = 0; mt < 4; mt++)
        #pragma unroll
        for (int nt = 0; nt < 4; nt++)
            acc[mt][nt] = (floatx4){0.f, 0.f, 0.f, 0.f};

    for (int k0 = koff; k0 < kend; k0 += 32) {
        #pragma unroll
        for (int it = 0; it < 2; it++) {
            int fl = tid + it * 256;
            int row = fl >> 2, ch = fl & 3;
            size_t ga = (a_row0 + row) * (size_t)K + k0 + ch * 8;
            size_t gw = (w_row0 + row) * (size_t)K + k0 + ch * 8;
            *(short8_t*)&As_h[row * PG + ch * 8] = *(const short8_t*)(Ah + ga);
            *(short8_t*)&As_l[row * PG + ch * 8] = *(const short8_t*)(Al + ga);
            *(short8_t*)&Ws_h[row * PG + ch * 8] = *(const short8_t*)(Wh + gw);
            *(short8_t*)&Ws_l[row * PG + ch * 8] = *(const short8_t*)(Wl + gw);
        }
        __syncthreads();
        short8_t afh[4], afl[4], bfh[4], bfl[4];
        #pragma unroll
        for (int mt = 0; mt < 4; mt++) {
            afh[mt] = *(const short8_t*)&As_h[(wm * 64 + mt * 16 + l16) * PG + quad * 8];
            afl[mt] = *(const short8_t*)&As_l[(wm * 64 + mt * 16 + l16) * PG + quad * 8];
        }
        #pragma unroll
        for (int nt = 0; nt < 4; nt++) {
            bfh[nt] = *(const short8_t*)&Ws_h[(wn * 64 + nt * 16 + l16) * PG + quad * 8];
            bfl[nt] = *(const short8_t*)&Ws_l[(wn * 64 + nt * 16 + l16) * PG + quad * 8];
        }
        #pragma unroll
        for (int mt = 0; mt < 4; mt++)
            #pragma unroll
            for (int nt = 0; nt < 4; nt++) {
                acc[mt][nt] = __builtin_amdgcn_mfma_f32_16x16x32_bf16(afh[mt], bfh[nt], acc[mt][nt], 0, 0, 0);
                acc[mt][nt] = __builtin_amdgcn_mfma_f32_16x16x32_bf16(afh[mt], bfl[nt], acc[mt][nt], 0, 0, 0);
                acc[mt][nt] = __builtin_amdgcn_mfma_f32_16x16x32_bf16(afl[mt], bfh[nt], acc[mt][nt], 0, 0, 0);
            }
        __syncthreads();
    }

    #pragma unroll
    for (int mt = 0; mt < 4; mt++) {
        #pragma unroll
        for (int r = 0; r < 4; r++) {
            size_t grow = out_row0 + wm * 64 + mt * 16 + quad * 4 + r;
            #pragma unroll
            for (int nt = 0; nt < 4; nt++) {
                int gcol = col0 + wn * 64 + nt * 16 + l16;
                float v = acc[mt][nt][r];
                if (MODE == 0) {
                    v = fmaxf(v, 0.f);
                    size_t o = grow * 1024 + gcol;
                    unsigned short hb = f2bf(v);
                    outh[o] = hb;
                    outl[o] = f2bf(v - bf2f(hb));
                    // fused rope: partner col (n^1) lives in lane l16^1
                    float vp = __shfl_xor(v, 1);
                    int n = gcol & 255, h = gcol >> 8;
                    int t = (int)(grow & 1023), b = (int)(grow >> 10);
                    int p = n >> 1, j = p & 63;
                    int pos = (p < 64) ? (t & 31) : (t >> 5);
                    float2 scs = rtab_s[j * 32 + pos];   // == (__sinf(ang), __cosf(ang))
                    float sn = scs.x, cs = scs.y;
                    float ro = (n & 1) ? (vp * sn + v * cs) : (v * cs - vp * sn);
                    size_t qo = (((size_t)b * NH_ + h) * T_ + t) * N_ + n;
                    unsigned short qb = f2bf(ro);
                    qrh[qo] = qb;
                    qrl[qo] = f2bf(ro - bf2f(qb));
                } else if (MODE == 1) {
                    float y = fmaxf(v, 0.f);
                    size_t o = grow * 1024 + gcol;
                    float xv = bf2f(xsh[o]) + bf2f(xsl[o]);
                    float p = xv * y;
                    unsigned short hb = f2bf(p);
                    outh[o] = hb;
                    outl[o] = f2bf(p - bf2f(hb));
                } else {
                    outf[(size_t)blockIdx.z * 2097152 + grow * 256 + gcol] = v;
                }
            }
        }
    }
}

// ---------- x (B,T,D) fp32 -> Vf hi/lo fragment-order bf16 ----------
__global__ __launch_bounds__(256) void k_xT(const float* __restrict__ x,
                                            unsigned short* __restrict__ Vfh,
                                            unsigned short* __restrict__ Vfl)
{
    __shared__ float tile[64][65];   // [t_local][d_local]
    int t0 = blockIdx.x * 64, d0 = blockIdx.y * 64, b = blockIdx.z;
    const float* src = x + ((size_t)b * T_ + t0) * D_ + d0;
    for (int i = threadIdx.x; i < 1024; i += 256) {
        int r = i >> 4, c = i & 15;
        float4 v = *(const float4*)(src + (size_t)r * D_ + c * 4);
        tile[r][c * 4 + 0] = v.x;
        tile[r][c * 4 + 1] = v.y;
        tile[r][c * 4 + 2] = v.z;
        tile[r][c * 4 + 3] = v.w;
    }
    __syncthreads();
    for (int i = threadIdx.x; i < 1024; i += 256) {
        int d = i >> 4, c = i & 15;          // d_local, t-group (4 consecutive t)
        int tg = t0 + c * 4;
        int jj = tg >> 5, qd = (tg >> 3) & 3, i8 = tg & 7;   // i8 in {0,4}
        int dg = d0 + d;
        int tn = dg >> 4, s16 = dg & 15;
        size_t o = (((size_t)b * 32 + jj) * 16 + tn) * 512 + (qd * 16 + s16) * 8 + i8;
        float v0 = tile[c * 4 + 0][d], v1 = tile[c * 4 + 1][d];
        float v2 = tile[c * 4 + 2][d], v3 = tile[c * 4 + 3][d];
        ushort4 oh, ol;
        oh.x = f2bf(v0); ol.x = f2bf(v0 - bf2f(oh.x));
        oh.y = f2bf(v1); ol.y = f2bf(v1 - bf2f(oh.y));
        oh.z = f2bf(v2); ol.z = f2bf(v2 - bf2f(oh.z));
        oh.w = f2bf(v3); ol.w = f2bf(v3 - bf2f(oh.w));
        *(ushort4*)(Vfh + o) = oh;
        *(ushort4*)(Vfl + o) = ol;
    }
}

// ---------- fused split-bf16 MFMA flash attention + /l + LayerNorm ----------
// Exact R5 kernel (best measured: 125.0 us). Pair-split: waves pair over a
// 32-row group (rg = w>>1, half = w&1). QK: 32 rows x 16 score cols/wave.
// PV: 32 rows x half-D/wave. P exchanged through LDS. 128 VGPR, no spill,
// 2 waves/SIMD.
#define PPW2 36   // P row pitch (32 cols + 4 pad)

__global__ __launch_bounds__(512, 1) void k_attn_mfma(
    const unsigned short* __restrict__ qr_h, const unsigned short* __restrict__ qr_l,
    const unsigned short* __restrict__ Vf_h, const unsigned short* __restrict__ Vf_l,
    unsigned short* __restrict__ ykvh, unsigned short* __restrict__ ykvl)
{
    __shared__ unsigned short K_h[2][16 * 512];   // 32 KB (2 buf, frag order)
    __shared__ unsigned short K_l[2][16 * 512];   // 32 KB
    __shared__ unsigned short V_h[2][16 * 512];   // 32 KB
    __shared__ unsigned short V_l[2][16 * 512];   // 32 KB
    __shared__ unsigned short P_h[4][32 * PPW2];  // 9216 B (per row-group)
    __shared__ unsigned short P_l[4][32 * PPW2];  // 9216 B
    __shared__ float l_scr[8][32];                // per-wave partial row sums
    __shared__ float s1_scr[8][32];               // per-wave partial LN stats
    __shared__ float s2_scr[8][32];

    int tid = threadIdx.x;
    int w = tid >> 6, lane = tid & 63, quad = lane >> 4, l16 = lane & 15;
    int rg = w >> 1, half = w & 1;
    int gid = blockIdx.x;
    int bh = gid & 31, tile = gid >> 5, b = bh >> 2;   // XCD swizzle: same-bh
    int t0q = tile * 128;                              // blocks share an XCD
    const unsigned short* qhb = qr_h + (size_t)bh * T_ * N_;
    const unsigned short* qlb = qr_l + (size_t)bh * T_ * N_;
    const unsigned short* vhb = Vf_h + (size_t)b * 32 * 16 * 512;
    const unsigned short* vlb = Vf_l + (size_t)b * 32 * 16 * 512;

    // Q A-frags: row-group's 32 rows (2 tiles of 16), full feature dim, hi+lo
    short8_t qfh[2][8], qfl[2][8];
    #pragma unroll
    for (int mt = 0; mt < 2; mt++)
        #pragma unroll
        for (int kc = 0; kc < 8; kc++) {
            size_t o = (size_t)(t0q + rg * 32 + mt * 16 + l16) * N_ + kc * 32 + quad * 8;
            qfh[mt][kc] = *(const short8_t*)(qhb + o);
            qfl[mt][kc] = *(const short8_t*)(qlb + o);
        }

    floatx4 O[2][8];                 // 32 rows x 128 cols (this wave's D-half)
    #pragma unroll
    for (int mt = 0; mt < 2; mt++)
        #pragma unroll
        for (int t = 0; t < 8; t++) O[mt][t] = (floatx4){0.f, 0.f, 0.f, 0.f};
    float lst[2][4] = {{0.f, 0.f, 0.f, 0.f}, {0.f, 0.f, 0.f, 0.f}};
    const float scale = 0.0625f;   // 1/sqrt(256)

    // preamble: stage K and V tile 0 into buffer 0 (wave w: slots 2w, 2w+1)
    #pragma unroll
    for (int s = 0; s < 2; s++) {
        int slot = w * 2 + s;
        int ct = slot >> 3, kc = slot & 7;
        size_t go = (size_t)(ct * 16 + l16) * N_ + kc * 32 + quad * 8;
        gload_lds16(qhb + go, &K_h[0][slot * 512]);
        gload_lds16(qlb + go, &K_l[0][slot * 512]);
        size_t vo = ((size_t)slot << 9) + lane * 8;
        gload_lds16(vhb + vo, &V_h[0][slot * 512]);
        gload_lds16(vlb + vo, &V_l[0][slot * 512]);
    }

    for (int j = 0; j < 32; j++) {
        int buf = j & 1;
        __syncthreads();            // [top] K(j),V(j) ready; drains K(j) loads
        if (j < 31) {               // stage V(j+1): lands during QK
            #pragma unroll
            for (int s = 0; s < 2; s++) {
                int slot = w * 2 + s;
                size_t vo = ((size_t)((j + 1) * 16 + slot) << 9) + lane * 8;
                gload_lds16(vhb + vo, &V_h[buf ^ 1][slot * 512]);
                gload_lds16(vlb + vo, &V_l[buf ^ 1][slot * 512]);
            }
        }

        // QK^T: this wave's 16 cols (ct = half) for 32 rows; 6 indep chains
        floatx4 a_hh0 = (floatx4){0.f, 0.f, 0.f, 0.f};
        floatx4 a_hl0 = (floatx4){0.f, 0.f, 0.f, 0.f};
        floatx4 a_lh0 = (floatx4){0.f, 0.f, 0.f, 0.f};
        floatx4 a_hh1 = (floatx4){0.f, 0.f, 0.f, 0.f};
        floatx4 a_hl1 = (floatx4){0.f, 0.f, 0.f, 0.f};
        floatx4 a_lh1 = (floatx4){0.f, 0.f, 0.f, 0.f};
        __builtin_amdgcn_s_setprio(1);
        #pragma unroll
        for (int kc = 0; kc < 8; kc++) {
            short8_t bkh = *(const short8_t*)&K_h[buf][(half * 8 + kc) * 512 + lane * 8];
            short8_t bkl = *(const short8_t*)&K_l[buf][(half * 8 + kc) * 512 + lane * 8];
            a_hh0 = __builtin_amdgcn_mfma_f32_16x16x32_bf16(qfh[0][kc], bkh, a_hh0, 0, 0, 0);
            a_hh1 = __builtin_amdgcn_mfma_f32_16x16x32_bf16(qfh[1][kc], bkh, a_hh1, 0, 0, 0);
            a_hl0 = __builtin_amdgcn_mfma_f32_16x16x32_bf16(qfh[0][kc], bkl, a_hl0, 0, 0, 0);
            a_hl1 = __builtin_amdgcn_mfma_f32_16x16x32_bf16(qfh[1][kc], bkl, a_hl1, 0, 0, 0);
            a_lh0 = __builtin_amdgcn_mfma_f32_16x16x32_bf16(qfl[0][kc], bkh, a_lh0, 0, 0, 0);
            a_lh1 = __builtin_amdgcn_mfma_f32_16x16x32_bf16(qfl[1][kc], bkh, a_lh1, 0, 0, 0);
        }
        __builtin_amdgcn_s_setprio(0);
        floatx4 sc0 = (a_hh0 + a_hl0) + a_lh0;
        floatx4 sc1 = (a_hh1 + a_hl1) + a_lh1;

        // fixed-shift softmax; write this wave's 16 cols into the rg P tile
        #pragma unroll
        for (int r = 0; r < 4; r++) {
            float p0 = __expf(sc0[r] * scale - 8.f);
            float p1 = __expf(sc1[r] * scale - 8.f);
            lst[0][r] += p0;
            lst[1][r] += p1;
            int row0 = quad * 4 + r, row1 = 16 + quad * 4 + r;
            unsigned short p0h = f2bf(p0), p1h = f2bf(p1);
            P_h[rg][row0 * PPW2 + half * 16 + l16] = p0h;
            P_h[rg][row1 * PPW2 + half * 16 + l16] = p1h;
            P_l[rg][row0 * PPW2 + half * 16 + l16] = f2bf(p0 - bf2f(p0h));
            P_l[rg][row1 * PPW2 + half * 16 + l16] = f2bf(p1 - bf2f(p1h));
        }

        __syncthreads();            // [mid] P complete (both halves); drains V(j+1)
        if (j < 31) {               // stage K(j+1): lands during PV
            #pragma unroll
            for (int s = 0; s < 2; s++) {
                int slot = w * 2 + s;
                int ct = slot >> 3, kc = slot & 7;
                size_t go = (size_t)((j + 1) * 32 + ct * 16 + l16) * N_ + kc * 32 + quad * 8;
                gload_lds16(qhb + go, &K_h[buf ^ 1][slot * 512]);
                gload_lds16(qlb + go, &K_l[buf ^ 1][slot * 512]);
            }
        }

        // P A-frags: full 32 cols (both halves) for both row tiles
        short8_t pah0 = *(const short8_t*)&P_h[rg][(l16) * PPW2 + quad * 8];
        short8_t pal0 = *(const short8_t*)&P_l[rg][(l16) * PPW2 + quad * 8];
        short8_t pah1 = *(const short8_t*)&P_h[rg][(16 + l16) * PPW2 + quad * 8];
        short8_t pal1 = *(const short8_t*)&P_l[rg][(16 + l16) * PPW2 + quad * 8];

        // PV: this wave's D-half (tn = half*8 + t); 3-term split, bit-identical
        __builtin_amdgcn_s_setprio(1);
        #pragma unroll
        for (int t = 0; t < 8; t++) {
            int tn = half * 8 + t;
            short8_t vbh = *(const short8_t*)&V_h[buf][tn * 512 + lane * 8];
            short8_t vbl = *(const short8_t*)&V_l[buf][tn * 512 + lane * 8];
            O[0][t] = __builtin_amdgcn_mfma_f32_16x16x32_bf16(pah0, vbh, O[0][t], 0, 0, 0);
            O[1][t] = __builtin_amdgcn_mfma_f32_16x16x32_bf16(pah1, vbh, O[1][t], 0, 0, 0);
            O[0][t] = __builtin_amdgcn_mfma_f32_16x16x32_bf16(pah0, vbl, O[0][t], 0, 0, 0);
            O[1][t] = __builtin_amdgcn_mfma_f32_16x16x32_bf16(pah1, vbl, O[1][t], 0, 0, 0);
            O[0][t] = __builtin_amdgcn_mfma_f32_16x16x32_bf16(pal0, vbh, O[0][t], 0, 0, 0);
            O[1][t] = __builtin_amdgcn_mfma_f32_16x16x32_bf16(pal1, vbh, O[1][t], 0, 0, 0);
        }
        __builtin_amdgcn_s_setprio(0);
    }

    // ---- epilogue: pair-merge l and LN stats through LDS, then write ----
    #pragma unroll
    for (int mt = 0; mt < 2; mt++)
        #pragma unroll
        for (int r = 0; r < 4; r++) {
            float ls = lst[mt][r];
            #pragma unroll
            for (int o = 1; o < 16; o <<= 1) ls += __shfl_xor(ls, o);
            float s1 = 0.f, s2 = 0.f;
            #pragma unroll
            for (int t = 0; t < 8; t++) { float v = O[mt][t][r]; s1 += v; s2 += v * v; }
            #pragma unroll
            for (int o = 1; o < 16; o <<= 1) { s1 += __shfl_xor(s1, o); s2 += __shfl_xor(s2, o); }
            int row = mt * 16 + quad * 4 + r;
            if (l16 == 0) { l_scr[w][row] = ls; s1_scr[w][row] = s1; s2_scr[w][row] = s2; }
        }
    __syncthreads();
    #pragma unroll
    for (int mt = 0; mt < 2; mt++)
        #pragma unroll
        for (int r = 0; r < 4; r++) {
            int row = mt * 16 + quad * 4 + r;
            float ls = l_scr[w][row] + l_scr[w ^ 1][row];
            float s1 = s1_scr[w][row] + s1_scr[w ^ 1][row];
            float s2 = s2_scr[w][row] + s2_scr[w ^ 1][row];
            float li = 1.f / ls;
            float mean = s1 * li * (1.f / 256.f);
            float e2   = s2 * li * li * (1.f / 256.f);
            float var  = e2 - mean * mean;
            float rs = rsqrtf(var + EPS_);
            float a = li * rs, bb = mean * rs;
            size_t obase = ((size_t)bh * T_ + t0q + rg * 32 + row) * D_;
            #pragma unroll
            for (int t = 0; t < 8; t++) {
                float v = O[mt][t][r] * a - bb;
                size_t o = obase + half * 128 + t * 16 + l16;
                unsigned short hb = f2bf(v);
                ykvh[o] = hb;
                ykvl[o] = f2bf(v - bf2f(hb));
            }
        }
}

// ---------- residual + double LN: sums 4 split-K partials of ymlp ----------
__global__ __launch_bounds__(256) void k_resid_ln(float* __restrict__ x,
                                                  const float* __restrict__ ymlp,
                                                  unsigned short* __restrict__ xh,
                                                  unsigned short* __restrict__ xl)
{
    __shared__ float red[8];
    int row = blockIdx.x, d = threadIdx.x;
    size_t o = (size_t)row * D_ + d;
    float y = ymlp[o] + ymlp[o + 2097152] + ymlp[o + 2 * 2097152] + ymlp[o + 3 * 2097152];
    float2 mv1 = block_stats_256(y, red);
    float v = x[o] + (y - mv1.x) * rsqrtf(mv1.y + EPS_);
    float2 mv2 = block_stats_256(v, red);
    float out = (v - mv2.x) * rsqrtf(mv2.y + EPS_);
    x[o] = out;
    unsigned short hb = f2bf(out);
    xh[o] = hb;
    xl[o] = f2bf(out - bf2f(hb));
}

// ---------- logits ----------
__global__ __launch_bounds__(256) void k_logits(
    const float* __restrict__ x, const float* __restrict__ out_w,
    const float* __restrict__ out_b, float* __restrict__ out)
{
    __shared__ float red[4];
    int row = blockIdx.x, d = threadIdx.x;
    float v = x[(size_t)row * D_ + d] * out_w[d];
    #pragma unroll
    for (int o = 32; o > 0; o >>= 1) v += __shfl_down(v, o);
    int wave = d >> 6, lane = d & 63;
    if (lane == 0) red[wave] = v;
    __syncthreads();
    if (d == 0) out[row] = red[0] + red[1] + red[2] + red[3] + out_b[0];
}

extern "C" void kernel_launch(void* const* d_in, const int* in_sizes, int n_in,
                              void* d_out, int out_size, void* d_ws, size_t ws_size,
                              hipStream_t stream)
{
    (void)in_sizes; (void)n_in; (void)out_size;
    if (ws_size < ((size_t)115 << 20)) return;

    const float* inputs    = (const float*)d_in[0];
    const float* in_w      = (const float*)d_in[1];
    const float* in_b      = (const float*)d_in[2];
    const float* encoder   = (const float*)d_in[3];
    const float* encoder_v = (const float*)d_in[4];
    const float* decoder   = (const float*)d_in[5];
    const float* out_w     = (const float*)d_in[6];
    const float* out_b     = (const float*)d_in[7];

    char* wsb = (char*)d_ws;
    float* x             = (float*)(wsb);                                 //  8 MB fp32 (B,T,D)
    unsigned short* x_h  = (unsigned short*)(wsb + ((size_t)8  << 20));   //  4 MB bf16 hi
    unsigned short* x_l  = (unsigned short*)(wsb + ((size_t)12 << 20));   //  4 MB lo
    unsigned short* Vf_h = x_h;                                           //  ALIAS (disjoint phases)
    unsigned short* Vf_l = x_l;
    unsigned short* xs_h = (unsigned short*)(wsb + ((size_t)16 << 20));   // 16 MB (B,T,NH*N) hi
    unsigned short* xs_l = (unsigned short*)(wsb + ((size_t)32 << 20));   // 16 MB lo
    float* ymlp          = (float*)(wsb + ((size_t)16 << 20));            // 32 MB fp32 x4 partials,
                                                                          //  ALIASES xs (dead there)
    unsigned short* qr_h = (unsigned short*)(wsb + ((size_t)48 << 20));   // 16 MB (B,NH,T,N) hi
    unsigned short* qr_l = (unsigned short*)(wsb + ((size_t)64 << 20));   // 16 MB lo
    unsigned short* xy_h = qr_h;                                          //  ALIAS: xy after attn
    unsigned short* xy_l = qr_l;
    unsigned short* ykv_h = (unsigned short*)(wsb + ((size_t)80 << 20));  // 16 MB (B,NH,T,D) hi
    unsigned short* ykv_l = (unsigned short*)(wsb + ((size_t)96 << 20));  // 16 MB lo
    char* wbase = wsb + ((size_t)112 << 20);                              //  3 MB weights (6 x 512 KB, FULL)
    unsigned short* encT_h = (unsigned short*)(wbase);
    unsigned short* encT_l = (unsigned short*)(wbase + 0x80000);
    unsigned short* evT_h  = (unsigned short*)(wbase + 2 * 0x80000);
    unsigned short* evT_l  = (unsigned short*)(wbase + 3 * 0x80000);
    unsigned short* decT_h = (unsigned short*)(wbase + 4 * 0x80000);
    unsigned short* decT_l = (unsigned short*)(wbase + 5 * 0x80000);

    k_wT<<<dim3(4, 4, 4), 256, 0, stream>>>(encoder,   encT_h, encT_l, 256, 256);
    k_wT<<<dim3(4, 4, 4), 256, 0, stream>>>(encoder_v, evT_h,  evT_l,  256, 256);
    k_wT<<<dim3(4, 16, 1), 256, 0, stream>>>(decoder,  decT_h, decT_l, 1024, 256);

    k_input_ln<<<B_ * T_, 256, 0, stream>>>(inputs, in_w, in_b, x, x_h, x_l);
    for (int l = 0; l < 3; l++) {
        k_gemm_mfma<0><<<dim3(8, 64, 1), 256, 0, stream>>>(
            x_h, x_l, encT_h, encT_l, nullptr, nullptr, xs_h, xs_l, nullptr, qr_h, qr_l);
        k_xT<<<dim3(16, 4, 8), 256, 0, stream>>>(x, Vf_h, Vf_l);
        k_attn_mfma<<<256, 512, 0, stream>>>(qr_h, qr_l, Vf_h, Vf_l, ykv_h, ykv_l);
        k_gemm_mfma<1><<<dim3(2, 8, 32), 256, 0, stream>>>(
            ykv_h, ykv_l, evT_h, evT_l, xs_h, xs_l, xy_h, xy_l, nullptr, nullptr, nullptr);
        k_gemm_mfma<2><<<dim3(2, 64, 4), 256, 0, stream>>>(
            xy_h, xy_l, decT_h, decT_l, nullptr, nullptr, nullptr, nullptr, ymlp, nullptr, nullptr);
        k_resid_ln<<<B_ * T_, 256, 0, stream>>>(x, ymlp, x_h, x_l);
    }
    k_logits<<<B_ * T_, 256, 0, stream>>>(x, out_w, out_b, (float*)d_out);
}

// Round 11
// 702.244 us; speedup vs baseline: 1.3346x; 1.0183x over previous
//
#include <hip/hip_runtime.h>
#include <hip/hip_bf16.h>
#include <math.h>

#define B_ 8
#define T_ 1024
#define D_ 256
#define NH_ 4
#define N_ 256
#define EPS_ 1e-5f

typedef __attribute__((ext_vector_type(8))) short short8_t;
typedef __attribute__((ext_vector_type(4))) float floatx4;

__device__ inline unsigned short f2bf(float f) {
    unsigned u = __builtin_bit_cast(unsigned, f);
    u += 0x7FFFu + ((u >> 16) & 1u);          // round-to-nearest-even
    return (unsigned short)(u >> 16);
}
__device__ inline float bf2f(unsigned short h) {
    return __builtin_bit_cast(float, (unsigned)h << 16);
}

// async global->LDS, 16 B per lane; lds base wave-uniform, HW adds lane*16
__device__ inline void gload_lds16(const unsigned short* g, unsigned short* l) {
    __builtin_amdgcn_global_load_lds(
        (const __attribute__((address_space(1))) unsigned int*)g,
        (__attribute__((address_space(3))) unsigned int*)l, 16, 0, 0);
}

// ---------- weight transpose + split ----------
__global__ __launch_bounds__(256) void k_wT(
    const float* __restrict__ in, unsigned short* __restrict__ outh,
    unsigned short* __restrict__ outl, int R, int C)
{
    __shared__ float tile[64][65];
    int c0 = blockIdx.x * 64, r0 = blockIdx.y * 64, h = blockIdx.z;
    in += (size_t)h * R * C;
    for (int i = threadIdx.x; i < 4096; i += 256) {
        int r = i >> 6, c = i & 63;
        tile[r][c] = in[(size_t)(r0 + r) * C + c0 + c];
    }
    __syncthreads();
    for (int i = threadIdx.x; i < 4096; i += 256) {
        int c = i >> 6, r = i & 63;
        float v = tile[r][c];
        unsigned short hb = f2bf(v);
        size_t o = (size_t)(h * C + c0 + c) * R + r0 + r;
        outh[o] = hb;
        outl[o] = f2bf(v - bf2f(hb));
    }
}

// ---------- input projection + LN: wave-per-row (4 rows/block, no barriers) ----------
__global__ __launch_bounds__(256) void k_input_ln(
    const float* __restrict__ inputs, const float* __restrict__ in_w,
    const float* __restrict__ in_b, float* __restrict__ x,
    unsigned short* __restrict__ xh, unsigned short* __restrict__ xl)
{
    int w = threadIdx.x >> 6, lane = threadIdx.x & 63;
    int row = blockIdx.x * 4 + w;
    float inp = inputs[row];
    int d0 = lane * 4;
    float4 wv = *(const float4*)(in_w + d0);
    float4 bv = *(const float4*)(in_b + d0);
    float v[4] = { inp * wv.x + bv.x, inp * wv.y + bv.y,
                   inp * wv.z + bv.z, inp * wv.w + bv.w };
    float s1 = 0.f, s2 = 0.f;
    #pragma unroll
    for (int i = 0; i < 4; i++) { s1 += v[i]; s2 += v[i] * v[i]; }
    #pragma unroll
    for (int o = 32; o > 0; o >>= 1) { s1 += __shfl_xor(s1, o); s2 += __shfl_xor(s2, o); }
    float mean = s1 * (1.f / 256.f);
    float var  = s2 * (1.f / 256.f) - mean * mean;
    float rs = rsqrtf(var + EPS_);
    size_t base = (size_t)row * D_ + d0;
    float4 xo; ushort4 oh, ol;
    float o0 = (v[0] - mean) * rs, o1 = (v[1] - mean) * rs;
    float o2 = (v[2] - mean) * rs, o3 = (v[3] - mean) * rs;
    xo.x = o0; xo.y = o1; xo.z = o2; xo.w = o3;
    oh.x = f2bf(o0); ol.x = f2bf(o0 - bf2f(oh.x));
    oh.y = f2bf(o1); ol.y = f2bf(o1 - bf2f(oh.y));
    oh.z = f2bf(o2); ol.z = f2bf(o2 - bf2f(oh.z));
    oh.w = f2bf(o3); ol.w = f2bf(o3 - bf2f(oh.w));
    *(float4*)(x + base) = xo;
    *(ushort4*)(xh + base) = oh;
    *(ushort4*)(xl + base) = ol;
}

// ---------- split-bf16 MFMA GEMM (BK=32, PG-padded reg staging: best measured) ----------
// (256,2): 2 blocks/CU — co-resident block covers staging latency.
// MODE 0: epilogue FUSES rope -> writes qr hi/lo directly. sin/cos come from
//   a 16 KB LDS table built once per block with the SAME __expf/__sinf/__cosf
//   intrinsics (bit-identical values). LDS 40+16=56 KB -> still 2 blocks/CU.
// MODE 2 split-K-4: blockIdx.z = kz, partials summed in k_resid_ln.
#define PG 40   // LDS pitch (32 + 8)
template<int MODE>
__global__ __launch_bounds__(256, 2) void k_gemm_mfma(
    const unsigned short* __restrict__ Ah, const unsigned short* __restrict__ Al,
    const unsigned short* __restrict__ Wh, const unsigned short* __restrict__ Wl,
    const unsigned short* __restrict__ xsh, const unsigned short* __restrict__ xsl,
    unsigned short* __restrict__ outh, unsigned short* __restrict__ outl,
    float* __restrict__ outf,
    unsigned short* __restrict__ qrh, unsigned short* __restrict__ qrl)
{
    constexpr int K = (MODE == 2) ? 1024 : 256;
    __shared__ unsigned short As_h[128 * PG], As_l[128 * PG];
    __shared__ unsigned short Ws_h[128 * PG], Ws_l[128 * PG];
    __shared__ float2 rtab_s[(MODE == 0) ? 2048 : 1];   // 16 KB (MODE0 only)
    int tid = threadIdx.x;
    int w = tid >> 6, lane = tid & 63, quad = lane >> 4, l16 = lane & 15;
    int wm = w >> 1, wn = w & 1;
    int m0 = blockIdx.y * 128, n0x = blockIdx.x * 128;
    size_t a_row0, w_row0, out_row0;
    int col0;
    int koff = 0, kend = K;
    if (MODE == 1) {
        int bh = blockIdx.z;
        a_row0 = (size_t)bh * 1024 + m0;
        w_row0 = (size_t)((bh & 3) * 256 + n0x);
        out_row0 = (size_t)(bh >> 2) * 1024 + m0;
        col0 = (bh & 3) * 256 + n0x;
    } else {
        a_row0 = m0; w_row0 = n0x; out_row0 = m0; col0 = n0x;
        if (MODE == 2) { koff = blockIdx.z * 256; kend = koff + 256; }
    }

    if (MODE == 0) {
        // build rope table: entry i=(j*32+pos); 8 entries/thread
        #pragma unroll
        for (int it = 0; it < 8; it++) {
            int i = tid * 8 + it;
            int j = i >> 5, pos = i & 31;
            float f = __expf((float)j * -0.14391156f);
            float ang = (float)pos * f;
            rtab_s[i] = make_float2(__sinf(ang), __cosf(ang));
        }
    }

    floatx4 acc[4][4];
    #pragma unroll
    for (int mt = 0; mt < 4; mt++)
        #pragma unroll
        for (int nt = 0; nt < 4; nt++)
            acc[mt][nt] = (floatx4){0.f, 0.f, 0.f, 0.f};

    for (int k0 = koff; k0 < kend; k0 += 32) {
        #pragma unroll
        for (int it = 0; it < 2; it++) {
            int fl = tid + it * 256;
            int row = fl >> 2, ch = fl & 3;
            size_t ga = (a_row0 + row) * (size_t)K + k0 + ch * 8;
            size_t gw = (w_row0 + row) * (size_t)K + k0 + ch * 8;
            *(short8_t*)&As_h[row * PG + ch * 8] = *(const short8_t*)(Ah + ga);
            *(short8_t*)&As_l[row * PG + ch * 8] = *(const short8_t*)(Al + ga);
            *(short8_t*)&Ws_h[row * PG + ch * 8] = *(const short8_t*)(Wh + gw);
            *(short8_t*)&Ws_l[row * PG + ch * 8] = *(const short8_t*)(Wl + gw);
        }
        __syncthreads();
        short8_t afh[4], afl[4], bfh[4], bfl[4];
        #pragma unroll
        for (int mt = 0; mt < 4; mt++) {
            afh[mt] = *(const short8_t*)&As_h[(wm * 64 + mt * 16 + l16) * PG + quad * 8];
            afl[mt] = *(const short8_t*)&As_l[(wm * 64 + mt * 16 + l16) * PG + quad * 8];
        }
        #pragma unroll
        for (int nt = 0; nt < 4; nt++) {
            bfh[nt] = *(const short8_t*)&Ws_h[(wn * 64 + nt * 16 + l16) * PG + quad * 8];
            bfl[nt] = *(const short8_t*)&Ws_l[(wn * 64 + nt * 16 + l16) * PG + quad * 8];
        }
        #pragma unroll
        for (int mt = 0; mt < 4; mt++)
            #pragma unroll
            for (int nt = 0; nt < 4; nt++) {
                acc[mt][nt] = __builtin_amdgcn_mfma_f32_16x16x32_bf16(afh[mt], bfh[nt], acc[mt][nt], 0, 0, 0);
                acc[mt][nt] = __builtin_amdgcn_mfma_f32_16x16x32_bf16(afh[mt], bfl[nt], acc[mt][nt], 0, 0, 0);
                acc[mt][nt] = __builtin_amdgcn_mfma_f32_16x16x32_bf16(afl[mt], bfh[nt], acc[mt][nt], 0, 0, 0);
            }
        __syncthreads();
    }

    #pragma unroll
    for (int mt = 0; mt < 4; mt++) {
        #pragma unroll
        for (int r = 0; r < 4; r++) {
            size_t grow = out_row0 + wm * 64 + mt * 16 + quad * 4 + r;
            #pragma unroll
            for (int nt = 0; nt < 4; nt++) {
                int gcol = col0 + wn * 64 + nt * 16 + l16;
                float v = acc[mt][nt][r];
                if (MODE == 0) {
                    v = fmaxf(v, 0.f);
                    size_t o = grow * 1024 + gcol;
                    unsigned short hb = f2bf(v);
                    outh[o] = hb;
                    outl[o] = f2bf(v - bf2f(hb));
                    // fused rope: partner col (n^1) lives in lane l16^1
                    float vp = __shfl_xor(v, 1);
                    int n = gcol & 255, h = gcol >> 8;
                    int t = (int)(grow & 1023), b = (int)(grow >> 10);
                    int p = n >> 1, j = p & 63;
                    int pos = (p < 64) ? (t & 31) : (t >> 5);
                    float2 scs = rtab_s[j * 32 + pos];   // == (__sinf(ang), __cosf(ang))
                    float sn = scs.x, cs = scs.y;
                    float ro = (n & 1) ? (vp * sn + v * cs) : (v * cs - vp * sn);
                    size_t qo = (((size_t)b * NH_ + h) * T_ + t) * N_ + n;
                    unsigned short qb = f2bf(ro);
                    qrh[qo] = qb;
                    qrl[qo] = f2bf(ro - bf2f(qb));
                } else if (MODE == 1) {
                    float y = fmaxf(v, 0.f);
                    size_t o = grow * 1024 + gcol;
                    float xv = bf2f(xsh[o]) + bf2f(xsl[o]);
                    float p = xv * y;
                    unsigned short hb = f2bf(p);
                    outh[o] = hb;
                    outl[o] = f2bf(p - bf2f(hb));
                } else {
                    outf[(size_t)blockIdx.z * 2097152 + grow * 256 + gcol] = v;
                }
            }
        }
    }
}

// ---------- x (B,T,D) fp32 -> Vf hi/lo fragment-order bf16 ----------
__global__ __launch_bounds__(256) void k_xT(const float* __restrict__ x,
                                            unsigned short* __restrict__ Vfh,
                                            unsigned short* __restrict__ Vfl)
{
    __shared__ float tile[64][65];   // [t_local][d_local]
    int t0 = blockIdx.x * 64, d0 = blockIdx.y * 64, b = blockIdx.z;
    const float* src = x + ((size_t)b * T_ + t0) * D_ + d0;
    for (int i = threadIdx.x; i < 1024; i += 256) {
        int r = i >> 4, c = i & 15;
        float4 v = *(const float4*)(src + (size_t)r * D_ + c * 4);
        tile[r][c * 4 + 0] = v.x;
        tile[r][c * 4 + 1] = v.y;
        tile[r][c * 4 + 2] = v.z;
        tile[r][c * 4 + 3] = v.w;
    }
    __syncthreads();
    for (int i = threadIdx.x; i < 1024; i += 256) {
        int d = i >> 4, c = i & 15;          // d_local, t-group (4 consecutive t)
        int tg = t0 + c * 4;
        int jj = tg >> 5, qd = (tg >> 3) & 3, i8 = tg & 7;   // i8 in {0,4}
        int dg = d0 + d;
        int tn = dg >> 4, s16 = dg & 15;
        size_t o = (((size_t)b * 32 + jj) * 16 + tn) * 512 + (qd * 16 + s16) * 8 + i8;
        float v0 = tile[c * 4 + 0][d], v1 = tile[c * 4 + 1][d];
        float v2 = tile[c * 4 + 2][d], v3 = tile[c * 4 + 3][d];
        ushort4 oh, ol;
        oh.x = f2bf(v0); ol.x = f2bf(v0 - bf2f(oh.x));
        oh.y = f2bf(v1); ol.y = f2bf(v1 - bf2f(oh.y));
        oh.z = f2bf(v2); ol.z = f2bf(v2 - bf2f(oh.z));
        oh.w = f2bf(v3); ol.w = f2bf(v3 - bf2f(oh.w));
        *(ushort4*)(Vfh + o) = oh;
        *(ushort4*)(Vfl + o) = ol;
    }
}

// ---------- fused split-bf16 MFMA flash attention + /l + LayerNorm ----------
// Exact R5 kernel (best measured: 125.0 us). Pair-split: waves pair over a
// 32-row group (rg = w>>1, half = w&1). QK: 32 rows x 16 score cols/wave.
// PV: 32 rows x half-D/wave. P exchanged through LDS. 128 VGPR, no spill,
// 2 waves/SIMD.
#define PPW2 36   // P row pitch (32 cols + 4 pad)

__global__ __launch_bounds__(512, 1) void k_attn_mfma(
    const unsigned short* __restrict__ qr_h, const unsigned short* __restrict__ qr_l,
    const unsigned short* __restrict__ Vf_h, const unsigned short* __restrict__ Vf_l,
    unsigned short* __restrict__ ykvh, unsigned short* __restrict__ ykvl)
{
    __shared__ unsigned short K_h[2][16 * 512];   // 32 KB (2 buf, frag order)
    __shared__ unsigned short K_l[2][16 * 512];   // 32 KB
    __shared__ unsigned short V_h[2][16 * 512];   // 32 KB
    __shared__ unsigned short V_l[2][16 * 512];   // 32 KB
    __shared__ unsigned short P_h[4][32 * PPW2];  // 9216 B (per row-group)
    __shared__ unsigned short P_l[4][32 * PPW2];  // 9216 B
    __shared__ float l_scr[8][32];                // per-wave partial row sums
    __shared__ float s1_scr[8][32];               // per-wave partial LN stats
    __shared__ float s2_scr[8][32];

    int tid = threadIdx.x;
    int w = tid >> 6, lane = tid & 63, quad = lane >> 4, l16 = lane & 15;
    int rg = w >> 1, half = w & 1;
    int gid = blockIdx.x;
    int bh = gid & 31, tile = gid >> 5, b = bh >> 2;   // XCD swizzle: same-bh
    int t0q = tile * 128;                              // blocks share an XCD
    const unsigned short* qhb = qr_h + (size_t)bh * T_ * N_;
    const unsigned short* qlb = qr_l + (size_t)bh * T_ * N_;
    const unsigned short* vhb = Vf_h + (size_t)b * 32 * 16 * 512;
    const unsigned short* vlb = Vf_l + (size_t)b * 32 * 16 * 512;

    // Q A-frags: row-group's 32 rows (2 tiles of 16), full feature dim, hi+lo
    short8_t qfh[2][8], qfl[2][8];
    #pragma unroll
    for (int mt = 0; mt < 2; mt++)
        #pragma unroll
        for (int kc = 0; kc < 8; kc++) {
            size_t o = (size_t)(t0q + rg * 32 + mt * 16 + l16) * N_ + kc * 32 + quad * 8;
            qfh[mt][kc] = *(const short8_t*)(qhb + o);
            qfl[mt][kc] = *(const short8_t*)(qlb + o);
        }

    floatx4 O[2][8];                 // 32 rows x 128 cols (this wave's D-half)
    #pragma unroll
    for (int mt = 0; mt < 2; mt++)
        #pragma unroll
        for (int t = 0; t < 8; t++) O[mt][t] = (floatx4){0.f, 0.f, 0.f, 0.f};
    float lst[2][4] = {{0.f, 0.f, 0.f, 0.f}, {0.f, 0.f, 0.f, 0.f}};
    const float scale = 0.0625f;   // 1/sqrt(256)

    // preamble: stage K and V tile 0 into buffer 0 (wave w: slots 2w, 2w+1)
    #pragma unroll
    for (int s = 0; s < 2; s++) {
        int slot = w * 2 + s;
        int ct = slot >> 3, kc = slot & 7;
        size_t go = (size_t)(ct * 16 + l16) * N_ + kc * 32 + quad * 8;
        gload_lds16(qhb + go, &K_h[0][slot * 512]);
        gload_lds16(qlb + go, &K_l[0][slot * 512]);
        size_t vo = ((size_t)slot << 9) + lane * 8;
        gload_lds16(vhb + vo, &V_h[0][slot * 512]);
        gload_lds16(vlb + vo, &V_l[0][slot * 512]);
    }

    for (int j = 0; j < 32; j++) {
        int buf = j & 1;
        __syncthreads();            // [top] K(j),V(j) ready; drains K(j) loads
        if (j < 31) {               // stage V(j+1): lands during QK
            #pragma unroll
            for (int s = 0; s < 2; s++) {
                int slot = w * 2 + s;
                size_t vo = ((size_t)((j + 1) * 16 + slot) << 9) + lane * 8;
                gload_lds16(vhb + vo, &V_h[buf ^ 1][slot * 512]);
                gload_lds16(vlb + vo, &V_l[buf ^ 1][slot * 512]);
            }
        }

        // QK^T: this wave's 16 cols (ct = half) for 32 rows; 6 indep chains
        floatx4 a_hh0 = (floatx4){0.f, 0.f, 0.f, 0.f};
        floatx4 a_hl0 = (floatx4){0.f, 0.f, 0.f, 0.f};
        floatx4 a_lh0 = (floatx4){0.f, 0.f, 0.f, 0.f};
        floatx4 a_hh1 = (floatx4){0.f, 0.f, 0.f, 0.f};
        floatx4 a_hl1 = (floatx4){0.f, 0.f, 0.f, 0.f};
        floatx4 a_lh1 = (floatx4){0.f, 0.f, 0.f, 0.f};
        __builtin_amdgcn_s_setprio(1);
        #pragma unroll
        for (int kc = 0; kc < 8; kc++) {
            short8_t bkh = *(const short8_t*)&K_h[buf][(half * 8 + kc) * 512 + lane * 8];
            short8_t bkl = *(const short8_t*)&K_l[buf][(half * 8 + kc) * 512 + lane * 8];
            a_hh0 = __builtin_amdgcn_mfma_f32_16x16x32_bf16(qfh[0][kc], bkh, a_hh0, 0, 0, 0);
            a_hh1 = __builtin_amdgcn_mfma_f32_16x16x32_bf16(qfh[1][kc], bkh, a_hh1, 0, 0, 0);
            a_hl0 = __builtin_amdgcn_mfma_f32_16x16x32_bf16(qfh[0][kc], bkl, a_hl0, 0, 0, 0);
            a_hl1 = __builtin_amdgcn_mfma_f32_16x16x32_bf16(qfh[1][kc], bkl, a_hl1, 0, 0, 0);
            a_lh0 = __builtin_amdgcn_mfma_f32_16x16x32_bf16(qfl[0][kc], bkh, a_lh0, 0, 0, 0);
            a_lh1 = __builtin_amdgcn_mfma_f32_16x16x32_bf16(qfl[1][kc], bkh, a_lh1, 0, 0, 0);
        }
        __builtin_amdgcn_s_setprio(0);
        floatx4 sc0 = (a_hh0 + a_hl0) + a_lh0;
        floatx4 sc1 = (a_hh1 + a_hl1) + a_lh1;

        // fixed-shift softmax; write this wave's 16 cols into the rg P tile
        #pragma unroll
        for (int r = 0; r < 4; r++) {
            float p0 = __expf(sc0[r] * scale - 8.f);
            float p1 = __expf(sc1[r] * scale - 8.f);
            lst[0][r] += p0;
            lst[1][r] += p1;
            int row0 = quad * 4 + r, row1 = 16 + quad * 4 + r;
            unsigned short p0h = f2bf(p0), p1h = f2bf(p1);
            P_h[rg][row0 * PPW2 + half * 16 + l16] = p0h;
            P_h[rg][row1 * PPW2 + half * 16 + l16] = p1h;
            P_l[rg][row0 * PPW2 + half * 16 + l16] = f2bf(p0 - bf2f(p0h));
            P_l[rg][row1 * PPW2 + half * 16 + l16] = f2bf(p1 - bf2f(p1h));
        }

        __syncthreads();            // [mid] P complete (both halves); drains V(j+1)
        if (j < 31) {               // stage K(j+1): lands during PV
            #pragma unroll
            for (int s = 0; s < 2; s++) {
                int slot = w * 2 + s;
                int ct = slot >> 3, kc = slot & 7;
                size_t go = (size_t)((j + 1) * 32 + ct * 16 + l16) * N_ + kc * 32 + quad * 8;
                gload_lds16(qhb + go, &K_h[buf ^ 1][slot * 512]);
                gload_lds16(qlb + go, &K_l[buf ^ 1][slot * 512]);
            }
        }

        // P A-frags: full 32 cols (both halves) for both row tiles
        short8_t pah0 = *(const short8_t*)&P_h[rg][(l16) * PPW2 + quad * 8];
        short8_t pal0 = *(const short8_t*)&P_l[rg][(l16) * PPW2 + quad * 8];
        short8_t pah1 = *(const short8_t*)&P_h[rg][(16 + l16) * PPW2 + quad * 8];
        short8_t pal1 = *(const short8_t*)&P_l[rg][(16 + l16) * PPW2 + quad * 8];

        // PV: this wave's D-half (tn = half*8 + t); 3-term split, bit-identical
        __builtin_amdgcn_s_setprio(1);
        #pragma unroll
        for (int t = 0; t < 8; t++) {
            int tn = half * 8 + t;
            short8_t vbh = *(const short8_t*)&V_h[buf][tn * 512 + lane * 8];
            short8_t vbl = *(const short8_t*)&V_l[buf][tn * 512 + lane * 8];
            O[0][t] = __builtin_amdgcn_mfma_f32_16x16x32_bf16(pah0, vbh, O[0][t], 0, 0, 0);
            O[1][t] = __builtin_amdgcn_mfma_f32_16x16x32_bf16(pah1, vbh, O[1][t], 0, 0, 0);
            O[0][t] = __builtin_amdgcn_mfma_f32_16x16x32_bf16(pah0, vbl, O[0][t], 0, 0, 0);
            O[1][t] = __builtin_amdgcn_mfma_f32_16x16x32_bf16(pah1, vbl, O[1][t], 0, 0, 0);
            O[0][t] = __builtin_amdgcn_mfma_f32_16x16x32_bf16(pal0, vbh, O[0][t], 0, 0, 0);
            O[1][t] = __builtin_amdgcn_mfma_f32_16x16x32_bf16(pal1, vbh, O[1][t], 0, 0, 0);
        }
        __builtin_amdgcn_s_setprio(0);
    }

    // ---- epilogue: pair-merge l and LN stats through LDS, then write ----
    #pragma unroll
    for (int mt = 0; mt < 2; mt++)
        #pragma unroll
        for (int r = 0; r < 4; r++) {
            float ls = lst[mt][r];
            #pragma unroll
            for (int o = 1; o < 16; o <<= 1) ls += __shfl_xor(ls, o);
            float s1 = 0.f, s2 = 0.f;
            #pragma unroll
            for (int t = 0; t < 8; t++) { float v = O[mt][t][r]; s1 += v; s2 += v * v; }
            #pragma unroll
            for (int o = 1; o < 16; o <<= 1) { s1 += __shfl_xor(s1, o); s2 += __shfl_xor(s2, o); }
            int row = mt * 16 + quad * 4 + r;
            if (l16 == 0) { l_scr[w][row] = ls; s1_scr[w][row] = s1; s2_scr[w][row] = s2; }
        }
    __syncthreads();
    #pragma unroll
    for (int mt = 0; mt < 2; mt++)
        #pragma unroll
        for (int r = 0; r < 4; r++) {
            int row = mt * 16 + quad * 4 + r;
            float ls = l_scr[w][row] + l_scr[w ^ 1][row];
            float s1 = s1_scr[w][row] + s1_scr[w ^ 1][row];
            float s2 = s2_scr[w][row] + s2_scr[w ^ 1][row];
            float li = 1.f / ls;
            float mean = s1 * li * (1.f / 256.f);
            float e2   = s2 * li * li * (1.f / 256.f);
            float var  = e2 - mean * mean;
            float rs = rsqrtf(var + EPS_);
            float a = li * rs, bb = mean * rs;
            size_t obase = ((size_t)bh * T_ + t0q + rg * 32 + row) * D_;
            #pragma unroll
            for (int t = 0; t < 8; t++) {
                float v = O[mt][t][r] * a - bb;
                size_t o = obase + half * 128 + t * 16 + l16;
                unsigned short hb = f2bf(v);
                ykvh[o] = hb;
                ykvl[o] = f2bf(v - bf2f(hb));
            }
        }
}

// ---------- residual + double LN: wave-per-row (4 rows/block, no barriers) ----------
__global__ __launch_bounds__(256) void k_resid_ln(float* __restrict__ x,
                                                  const float* __restrict__ ymlp,
                                                  unsigned short* __restrict__ xh,
                                                  unsigned short* __restrict__ xl)
{
    int w = threadIdx.x >> 6, lane = threadIdx.x & 63;
    int row = blockIdx.x * 4 + w;
    size_t base = (size_t)row * D_ + lane * 4;
    float4 y0 = *(const float4*)(ymlp + base);
    float4 y1 = *(const float4*)(ymlp + base + 2097152);
    float4 y2 = *(const float4*)(ymlp + base + 2 * 2097152);
    float4 y3 = *(const float4*)(ymlp + base + 3 * 2097152);
    float y[4] = { y0.x + y1.x + y2.x + y3.x, y0.y + y1.y + y2.y + y3.y,
                   y0.z + y1.z + y2.z + y3.z, y0.w + y1.w + y2.w + y3.w };
    float s1 = 0.f, s2 = 0.f;
    #pragma unroll
    for (int i = 0; i < 4; i++) { s1 += y[i]; s2 += y[i] * y[i]; }
    #pragma unroll
    for (int o = 32; o > 0; o >>= 1) { s1 += __shfl_xor(s1, o); s2 += __shfl_xor(s2, o); }
    float m1 = s1 * (1.f / 256.f);
    float var1 = s2 * (1.f / 256.f) - m1 * m1;
    float rs1 = rsqrtf(var1 + EPS_);
    float4 xv = *(const float4*)(x + base);
    float v[4] = { xv.x + (y[0] - m1) * rs1, xv.y + (y[1] - m1) * rs1,
                   xv.z + (y[2] - m1) * rs1, xv.w + (y[3] - m1) * rs1 };
    float t1 = 0.f, t2 = 0.f;
    #pragma unroll
    for (int i = 0; i < 4; i++) { t1 += v[i]; t2 += v[i] * v[i]; }
    #pragma unroll
    for (int o = 32; o > 0; o >>= 1) { t1 += __shfl_xor(t1, o); t2 += __shfl_xor(t2, o); }
    float m2 = t1 * (1.f / 256.f);
    float var2 = t2 * (1.f / 256.f) - m2 * m2;
    float rs2 = rsqrtf(var2 + EPS_);
    float4 xo; ushort4 oh, ol;
    float o0 = (v[0] - m2) * rs2, o1 = (v[1] - m2) * rs2;
    float o2 = (v[2] - m2) * rs2, o3 = (v[3] - m2) * rs2;
    xo.x = o0; xo.y = o1; xo.z = o2; xo.w = o3;
    oh.x = f2bf(o0); ol.x = f2bf(o0 - bf2f(oh.x));
    oh.y = f2bf(o1); ol.y = f2bf(o1 - bf2f(oh.y));
    oh.z = f2bf(o2); ol.z = f2bf(o2 - bf2f(oh.z));
    oh.w = f2bf(o3); ol.w = f2bf(o3 - bf2f(oh.w));
    *(float4*)(x + base) = xo;
    *(ushort4*)(xh + base) = oh;
    *(ushort4*)(xl + base) = ol;
}

// ---------- logits: wave-per-row (4 rows/block) ----------
__global__ __launch_bounds__(256) void k_logits(
    const float* __restrict__ x, const float* __restrict__ out_w,
    const float* __restrict__ out_b, float* __restrict__ out)
{
    int w = threadIdx.x >> 6, lane = threadIdx.x & 63;
    int row = blockIdx.x * 4 + w;
    size_t base = (size_t)row * D_ + lane * 4;
    float4 xv = *(const float4*)(x + base);
    float4 wv = *(const float4*)(out_w + lane * 4);
    float v = xv.x * wv.x + xv.y * wv.y + xv.z * wv.z + xv.w * wv.w;
    #pragma unroll
    for (int o = 32; o > 0; o >>= 1) v += __shfl_xor(v, o);
    if (lane == 0) out[row] = v + out_b[0];
}

extern "C" void kernel_launch(void* const* d_in, const int* in_sizes, int n_in,
                              void* d_out, int out_size, void* d_ws, size_t ws_size,
                              hipStream_t stream)
{
    (void)in_sizes; (void)n_in; (void)out_size;
    if (ws_size < ((size_t)115 << 20)) return;

    const float* inputs    = (const float*)d_in[0];
    const float* in_w      = (const float*)d_in[1];
    const float* in_b      = (const float*)d_in[2];
    const float* encoder   = (const float*)d_in[3];
    const float* encoder_v = (const float*)d_in[4];
    const float* decoder   = (const float*)d_in[5];
    const float* out_w     = (const float*)d_in[6];
    const float* out_b     = (const float*)d_in[7];

    char* wsb = (char*)d_ws;
    float* x             = (float*)(wsb);                                 //  8 MB fp32 (B,T,D)
    unsigned short* x_h  = (unsigned short*)(wsb + ((size_t)8  << 20));   //  4 MB bf16 hi
    unsigned short* x_l  = (unsigned short*)(wsb + ((size_t)12 << 20));   //  4 MB lo
    unsigned short* Vf_h = x_h;                                           //  ALIAS (disjoint phases)
    unsigned short* Vf_l = x_l;
    unsigned short* xs_h = (unsigned short*)(wsb + ((size_t)16 << 20));   // 16 MB (B,T,NH*N) hi
    unsigned short* xs_l = (unsigned short*)(wsb + ((size_t)32 << 20));   // 16 MB lo
    float* ymlp          = (float*)(wsb + ((size_t)16 << 20));            // 32 MB fp32 x4 partials,
                                                                          //  ALIASES xs (dead there)
    unsigned short* qr_h = (unsigned short*)(wsb + ((size_t)48 << 20));   // 16 MB (B,NH,T,N) hi
    unsigned short* qr_l = (unsigned short*)(wsb + ((size_t)64 << 20));   // 16 MB lo
    unsigned short* xy_h = qr_h;                                          //  ALIAS: xy after attn
    unsigned short* xy_l = qr_l;
    unsigned short* ykv_h = (unsigned short*)(wsb + ((size_t)80 << 20));  // 16 MB (B,NH,T,D) hi
    unsigned short* ykv_l = (unsigned short*)(wsb + ((size_t)96 << 20));  // 16 MB lo
    char* wbase = wsb + ((size_t)112 << 20);                              //  3 MB weights (6 x 512 KB, FULL)
    unsigned short* encT_h = (unsigned short*)(wbase);
    unsigned short* encT_l = (unsigned short*)(wbase + 0x80000);
    unsigned short* evT_h  = (unsigned short*)(wbase + 2 * 0x80000);
    unsigned short* evT_l  = (unsigned short*)(wbase + 3 * 0x80000);
    unsigned short* decT_h = (unsigned short*)(wbase + 4 * 0x80000);
    unsigned short* decT_l = (unsigned short*)(wbase + 5 * 0x80000);

    k_wT<<<dim3(4, 4, 4), 256, 0, stream>>>(encoder,   encT_h, encT_l, 256, 256);
    k_wT<<<dim3(4, 4, 4), 256, 0, stream>>>(encoder_v, evT_h,  evT_l,  256, 256);
    k_wT<<<dim3(4, 16, 1), 256, 0, stream>>>(decoder,  decT_h, decT_l, 1024, 256);

    k_input_ln<<<B_ * T_ / 4, 256, 0, stream>>>(inputs, in_w, in_b, x, x_h, x_l);
    for (int l = 0; l < 3; l++) {
        k_gemm_mfma<0><<<dim3(8, 64, 1), 256, 0, stream>>>(
            x_h, x_l, encT_h, encT_l, nullptr, nullptr, xs_h, xs_l, nullptr, qr_h, qr_l);
        k_xT<<<dim3(16, 4, 8), 256, 0, stream>>>(x, Vf_h, Vf_l);
        k_attn_mfma<<<256, 512, 0, stream>>>(qr_h, qr_l, Vf_h, Vf_l, ykv_h, ykv_l);
        k_gemm_mfma<1><<<dim3(2, 8, 32), 256, 0, stream>>>(
            ykv_h, ykv_l, evT_h, evT_l, xs_h, xs_l, xy_h, xy_l, nullptr, nullptr, nullptr);
        k_gemm_mfma<2><<<dim3(2, 64, 4), 256, 0, stream>>>(
            xy_h, xy_l, decT_h, decT_l, nullptr, nullptr, nullptr, nullptr, ymlp, nullptr, nullptr);
        k_resid_ln<<<B_ * T_ / 4, 256, 0, stream>>>(x, ymlp, x_h, x_l);
    }
    k_logits<<<B_ * T_ / 4, 256, 0, stream>>>(x, out_w, out_b, (float*)d_out);
}